// Round 10
// baseline (145.884 us; speedup 1.0000x reference)
//
#include <hip/hip_runtime.h>

// MHA: B=2, S=2048, D=1024, H=16, HD=64, causal, scale=1/8.
// Round 10: fix compile error only (cast d_out to float* for gemm128o).
// Structure identical to round 9: QKV -> 256^2 8-wave phase-paced template,
// attn4 split-KV, out-proj 128^2 2-phase dbuf.
//   ws layout (bytes):
//     [0,8M)    Xbf  : x as bf16 [4096,1024]
//     [8M,16M)  WT   : WqT,WkT,WvT,WoT bf16 [1024,1024] each ([N][K])
//     [16M,40M) QKV  : Q [B,H,S,HD], K [B,H,S,HD], Vt [B,H,HD,S] bf16
//     [40M,48M) ctx  : attention output bf16 [B,S,D]

#define S_LEN 2048
#define DMODEL 1024
#define NHEAD 16
#define HDIM 64
#define MROWS 4096  // B*S

typedef __bf16 bf16x8 __attribute__((ext_vector_type(8)));
typedef float f32x4 __attribute__((ext_vector_type(4)));
typedef float f32x16 __attribute__((ext_vector_type(16)));

__device__ __forceinline__ ushort f2bf(float f) {
  union { float f; unsigned u; } v; v.f = f;
  unsigned r = v.u + 0x7fffu + ((v.u >> 16) & 1u);  // RNE
  return (ushort)(r >> 16);
}

__device__ __forceinline__ void gload_lds16(const ushort* g, ushort* l) {
  __builtin_amdgcn_global_load_lds(
      (const __attribute__((address_space(1))) void*)g,
      (__attribute__((address_space(3))) void*)l, 16, 0, 0);
}

// pack two f32 -> one dword of 2 bf16 (compiler emits v_cvt_pk_bf16_f32)
__device__ __forceinline__ unsigned pack2bf(float lo, float hi) {
  union { __bf16 h[2]; unsigned u; } t;
  t.h[0] = (__bf16)lo; t.h[1] = (__bf16)hi;
  return t.u;
}

// ---------------- conversion kernels ----------------

__global__ __launch_bounds__(256) void cvt_x(const float* __restrict__ x,
                                             ushort* __restrict__ xb) {
  int i = (blockIdx.x * 256 + threadIdx.x) * 4;
  float4 v = *(const float4*)&x[i];
  ushort4 o;
  o.x = f2bf(v.x); o.y = f2bf(v.y); o.z = f2bf(v.z); o.w = f2bf(v.w);
  *(ushort4*)&xb[i] = o;
}

// W [K][N] fp32 -> WT [N][K] bf16
__global__ __launch_bounds__(256) void cvt_wt(const float* __restrict__ W0,
                                              const float* __restrict__ W1,
                                              const float* __restrict__ W2,
                                              const float* __restrict__ W3,
                                              ushort* __restrict__ out) {
  const float* W = blockIdx.z == 0 ? W0 : blockIdx.z == 1 ? W1
                   : blockIdx.z == 2 ? W2 : W3;
  ushort* WT = out + (size_t)blockIdx.z * DMODEL * DMODEL;
  __shared__ float tile[32][33];
  int n0 = blockIdx.x * 32, k0 = blockIdx.y * 32;
  int tx = threadIdx.x & 31, ty = threadIdx.x >> 5;  // 32 x 8
#pragma unroll
  for (int i = 0; i < 32; i += 8)
    tile[ty + i][tx] = W[(size_t)(k0 + ty + i) * DMODEL + n0 + tx];
  __syncthreads();
#pragma unroll
  for (int i = 0; i < 32; i += 8)
    WT[(size_t)(n0 + ty + i) * DMODEL + k0 + tx] = f2bf(tile[tx][ty + i]);
}

// ---------------- QKV GEMM: 256x256 tile, 8 waves, phase-paced ------------
// A = Xbf [4096,1024]; Bt = WT [3072 rows][1024] (QKV fused, rows contiguous).
// Out: bf16 QKV scatter (z = col>>10).
__global__ __launch_bounds__(512) void gemm256(
    const ushort* __restrict__ A, const ushort* __restrict__ Bt,
    const float* __restrict__ b0, const float* __restrict__ b1,
    const float* __restrict__ b2, ushort* __restrict__ outB) {
  const int flat = blockIdx.y * 16 + blockIdx.x;       // 0..191
  const int swz = (flat & 7) * 24 + (flat >> 3);       // bijective (192=8*24)
  const int bx = swz & 15, by = swz >> 4;
  const int m0 = bx * 256, n0 = by * 256;

  __shared__ __align__(16) ushort Al[2][256 * 64];  // 64 KB
  __shared__ __align__(16) ushort Bl[2][256 * 64];  // 64 KB

  const int tid = threadIdx.x;
  const int lane = tid & 63, wid = tid >> 6;
  const int wr = wid >> 2, wc = wid & 3;   // wave tile: rows wr*128, cols wc*64
  const int fr = lane & 15, hi16 = lane >> 4;

  f32x4 acc[8][4] = {};

  // ---- prologue: stage K-tile 0 into buf 0 (4 half-tiles) ----
#pragma unroll
  for (int htk = 0; htk < 4; ++htk) {
#pragma unroll
    for (int l = 0; l < 2; ++l) {
      int chunk = l * 512 + tid;               // 0..1023 within half-tile
      int row = chunk >> 3, cpos = chunk & 7;
      int scol = (cpos ^ (row & 7)) * 8;       // inverse-swizzled source col
      if (htk < 2)
        gload_lds16(&A[(size_t)(m0 + htk * 128 + row) * DMODEL + scol],
                    &Al[0][(htk * 1024 + chunk) * 8]);
      else
        gload_lds16(&Bt[(size_t)(n0 + (htk - 2) * 128 + row) * DMODEL + scol],
                    &Bl[0][((htk - 2) * 1024 + chunk) * 8]);
    }
  }
  __syncthreads();  // vmcnt drained: buf0 ready

  for (int t = 0; t < 16; ++t) {
    const int bt = t & 1;
    bf16x8 bfr[4];
#pragma unroll
    for (int s = 0; s < 4; ++s) {
      const int kk = s >> 1, mh = s & 1;
      // ds-read this sub-phase's register subtile (swizzled)
      bf16x8 af[4];
#pragma unroll
      for (int q = 0; q < 4; ++q) {
        int rl = wr * 128 + (mh * 4 + q) * 16 + fr;
        af[q] = *(const bf16x8*)&Al[bt][rl * 64 +
                                        ((kk * 4 + hi16) ^ (rl & 7)) * 8];
      }
      if (mh == 0) {
#pragma unroll
        for (int nf = 0; nf < 4; ++nf) {
          int rl = wc * 64 + nf * 16 + fr;
          bfr[nf] = *(const bf16x8*)&Bl[bt][rl * 64 +
                                            ((kk * 4 + hi16) ^ (rl & 7)) * 8];
        }
      }
      // stage ONE half-tile of K-tile t+1 into buf^1 (s: A-h0,A-h1,B-h0,B-h1)
      if (t + 1 < 16) {
        const int k64 = (t + 1) * 64;
#pragma unroll
        for (int l = 0; l < 2; ++l) {
          int chunk = l * 512 + tid;
          int row = chunk >> 3, cpos = chunk & 7;
          int scol = (cpos ^ (row & 7)) * 8;
          if (s < 2)
            gload_lds16(&A[(size_t)(m0 + s * 128 + row) * DMODEL + k64 + scol],
                        &Al[bt ^ 1][(s * 1024 + chunk) * 8]);
          else
            gload_lds16(
                &Bt[(size_t)(n0 + (s - 2) * 128 + row) * DMODEL + k64 + scol],
                &Bl[bt ^ 1][((s - 2) * 1024 + chunk) * 8]);
        }
      }
      __builtin_amdgcn_s_barrier();  // pacing: align waves into MFMA cluster
      __builtin_amdgcn_s_setprio(1);
#pragma unroll
      for (int q = 0; q < 4; ++q)
#pragma unroll
        for (int nf = 0; nf < 4; ++nf)
          acc[mh * 4 + q][nf] = __builtin_amdgcn_mfma_f32_16x16x32_bf16(
              af[q], bfr[nf], acc[mh * 4 + q][nf], 0, 0, 0);
      __builtin_amdgcn_s_setprio(0);
      if (s < 3) __builtin_amdgcn_s_barrier();
    }
    __syncthreads();  // buf bt reads done + tile t+1 stage drained (vmcnt 0)
  }

  // ---- epilogue: bias + QKV scatter ----
#pragma unroll
  for (int mf = 0; mf < 8; ++mf) {
#pragma unroll
    for (int nf = 0; nf < 4; ++nf) {
      int col = n0 + wc * 64 + nf * 16 + fr;  // 0..3071
      int z = col >> 10, cw = col & 1023;
      float bval = z == 0 ? b0[cw] : z == 1 ? b1[cw] : b2[cw];
      int h = cw >> 6, hd = cw & (HDIM - 1);
#pragma unroll
      for (int rg = 0; rg < 4; ++rg) {
        int row = m0 + wr * 128 + mf * 16 + hi16 * 4 + rg;
        int b = row >> 11, sq = row & (S_LEN - 1);
        float val = acc[mf][nf][rg] + bval;
        size_t idx;
        if (z < 2) idx = (((size_t)(b * NHEAD + h)) * S_LEN + sq) * HDIM + hd;
        else       idx = (((size_t)(b * NHEAD + h)) * HDIM + hd) * S_LEN + sq;
        outB[(size_t)z * MROWS * DMODEL + idx] = f2bf(val);
      }
    }
  }
}

// ---------------- out-proj GEMM (128x128 tile, BK=64, 2-phase dbuf) -------
__global__ __launch_bounds__(256) void gemm128o(
    const ushort* __restrict__ A, const ushort* __restrict__ Bt,
    const float* __restrict__ b0, float* __restrict__ outB) {
  const int NT = 256;
  const int flat = blockIdx.y * 32 + blockIdx.x;
  const int swz = (flat & 7) * (NT >> 3) + (flat >> 3);
  const int bx = swz & 31, by = swz >> 5;
  const int m0 = bx * 128, n0 = by * 128;

  __shared__ __align__(16) ushort Alds[2][128 * 64];
  __shared__ __align__(16) ushort Blds[2][128 * 64];

  const int tid = threadIdx.x;
  const int lane = tid & 63, w = tid >> 6;
  const int wr = w >> 1, wc = w & 1;
  const int fr = lane & 15, hi16 = lane >> 4;

  f32x4 acc[4][4] = {};

  auto STAGE = [&](int kt, int bi) {
#pragma unroll
    for (int it = 0; it < 4; ++it) {
      int c = it * 256 + tid;
      int row = c >> 3;
      int sc = ((c & 7) ^ (row & 7)) * 8;
      int ldsbase = (it * 256 + w * 64) * 8;
      gload_lds16(&A[(size_t)(m0 + row) * DMODEL + kt + sc],
                  &Alds[bi][ldsbase]);
      gload_lds16(&Bt[(size_t)(n0 + row) * DMODEL + kt + sc],
                  &Blds[bi][ldsbase]);
    }
  };

  auto COMPUTE = [&](int bi) {
#pragma unroll
    for (int kk = 0; kk < 2; ++kk) {
      bf16x8 af[4], bfr[4];
#pragma unroll
      for (int i = 0; i < 4; ++i) {
        int row = wr * 64 + i * 16 + fr;
        af[i] = *(const bf16x8*)&Alds[bi][row * 64 +
                                          ((kk * 4 + hi16) ^ (row & 7)) * 8];
      }
#pragma unroll
      for (int j = 0; j < 4; ++j) {
        int row = wc * 64 + j * 16 + fr;
        bfr[j] = *(const bf16x8*)&Blds[bi][row * 64 +
                                           ((kk * 4 + hi16) ^ (row & 7)) * 8];
      }
#pragma unroll
      for (int i = 0; i < 4; ++i)
#pragma unroll
        for (int j = 0; j < 4; ++j)
          acc[i][j] = __builtin_amdgcn_mfma_f32_16x16x32_bf16(af[i], bfr[j],
                                                              acc[i][j], 0, 0, 0);
    }
  };

  STAGE(0, 0);
  __syncthreads();
  int buf = 0;
  for (int kt = 64; kt < DMODEL; kt += 64) {
    STAGE(kt, buf ^ 1);
    COMPUTE(buf);
    __syncthreads();
    buf ^= 1;
  }
  COMPUTE(buf);

#pragma unroll
  for (int i = 0; i < 4; ++i) {
#pragma unroll
    for (int j = 0; j < 4; ++j) {
      int col = n0 + wc * 64 + j * 16 + fr;
      float bval = b0[col];
#pragma unroll
      for (int r = 0; r < 4; ++r) {
        int row = m0 + wr * 64 + i * 16 + hi16 * 4 + r;
        outB[(size_t)row * DMODEL + col] = acc[i][j][r] + bval;
      }
    }
  }
}

// ---------------- flash attention (causal), split-KV 4-wave ----------------
// (unchanged from round 8)
__global__ __launch_bounds__(256, 2) void attn4(const ushort* __restrict__ Q,
                                                const ushort* __restrict__ K,
                                                const ushort* __restrict__ Vt,
                                                ushort* __restrict__ ctx) {
  const int n = blockIdx.x;
  const int v = (n & 7) * 64 + (n >> 3);  // bijective XCD-contiguous (512=8*64)
  const int ptile = v & 15, bh = v >> 4;
  const int b = bh >> 4, h = bh & 15;
  const int tid = threadIdx.x;
  const int lane = tid & 63, wid = tid >> 6;
  const int p = wid >> 1;        // KV-parity pair: 0 even steps, 1 odd
  const int wq = wid & 1;        // 32-row q-subtile within the 64-row tile
  const int q32 = lane & 31, hi = lane >> 5;
  const bool lo_half = (hi == 0);
  const int tid2 = tid & 127;    // pair-local thread id (2 waves = 128 thr)

  const ushort* Qb = Q + (size_t)bh * S_LEN * HDIM;
  const ushort* Kb = K + (size_t)bh * S_LEN * HDIM;
  const ushort* Vb = Vt + (size_t)bh * HDIM * S_LEN;

  __shared__ __align__(16) ushort Kl[2][2][64 * 64];  // [pair][buf] 32 KB
  __shared__ __align__(16) ushort Vl[2][2][64 * 64];  // 32 KB
  float* scr = (float*)&Kl[0][0][0];  // merge scratch overlay (post-loop only)

  const float C = 0.125f * 1.44269504f;  // scale * log2(e)

  for (int ph = 0; ph < 2; ++ph) {
    const int j = ph ? 31 - ptile : ptile;  // 64-row q-tile index, 0..31
    const int qbase = j * 64 + wq * 32;
    const int qrow = qbase + q32;

    bf16x8 qf[4];
#pragma unroll
    for (int s = 0; s < 4; ++s)
      qf[s] = *(const bf16x8*)&Qb[(size_t)qrow * HDIM + s * 16 + hi * 8];

    f32x16 oacc[2] = {};
    float mraw = -1e30f, lsum = 0.f;
    const int NS = (j >> 1) + 1;  // iterations (pair0 steps; pair1 <= this)

    // prologue: pair p stages its first step (s0 = p) into buf 0
    if (p <= j) {
      const int kv = p * 64;
#pragma unroll
      for (int it = 0; it < 4; ++it) {
        int chunk = it * 128 + tid2;
        int row = chunk >> 3, sc = ((chunk & 7) ^ (row & 7)) * 8;
        gload_lds16(&Kb[(size_t)(kv + row) * HDIM + sc], &Kl[p][0][chunk * 8]);
        gload_lds16(&Vb[(size_t)row * S_LEN + kv + sc], &Vl[p][0][chunk * 8]);
      }
    }
    __syncthreads();

    int buf = 0;
    for (int it = 0; it < NS; ++it) {
      const int s = 2 * it + p;      // my global KV step
      const int kv0 = s * 64;

      // issue my pair's next-tile stage (s+2) first — overlaps compute
      if (s + 2 <= j) {
        const int kvn = kv0 + 128;
#pragma unroll
        for (int st = 0; st < 4; ++st) {
          int chunk = st * 128 + tid2;
          int row = chunk >> 3, sc = ((chunk & 7) ^ (row & 7)) * 8;
          gload_lds16(&Kb[(size_t)(kvn + row) * HDIM + sc],
                      &Kl[p][buf ^ 1][chunk * 8]);
          gload_lds16(&Vb[(size_t)row * S_LEN + kvn + sc],
                      &Vl[p][buf ^ 1][chunk * 8]);
        }
      }

      if (s <= j) {
        // ---- QK^T: S^T[k][q], 2 tiles of 32 k ----
        f32x16 sa[2] = {};
        __builtin_amdgcn_s_setprio(1);
#pragma unroll
        for (int t = 0; t < 2; ++t) {
          const int row = t * 32 + q32;
          const int rsw = (row & 7);
#pragma unroll
          for (int sl = 0; sl < 4; ++sl) {
            bf16x8 kf = *(const bf16x8*)&Kl[p][buf][row * 64 +
                                                    ((sl * 2 + hi) ^ rsw) * 8];
            sa[t] = __builtin_amdgcn_mfma_f32_32x32x16_bf16(kf, qf[sl], sa[t],
                                                            0, 0, 0);
          }
        }
        __builtin_amdgcn_s_setprio(0);

        // ---- V^T A-frags from LDS ----
        bf16x8 vf[2][4];
#pragma unroll
        for (int t2 = 0; t2 < 2; ++t2) {
          const int row = t2 * 32 + q32;
          const int rsw = (row & 7);
#pragma unroll
          for (int sl = 0; sl < 4; ++sl)
            vf[t2][sl] = *(const bf16x8*)&Vl[p][buf][row * 64 +
                                                     ((sl * 2 + hi) ^ rsw) * 8];
        }

        // ---- causal mask (only step s == j masks; wave-uniform) ----
        if (kv0 + 63 > qbase) {
          const int khi = kv0 + 4 * hi;
#pragma unroll
          for (int t = 0; t < 2; ++t)
#pragma unroll
            for (int r = 0; r < 16; ++r) {
              int kg = khi + t * 32 + (r & 3) + 8 * (r >> 2);
              if (kg > qrow) sa[t][r] = -1e30f;
            }
        }

        // ---- online softmax (raw domain; lane-local rows) ----
        float tm = sa[0][0];
#pragma unroll
        for (int r = 1; r < 16; ++r) tm = fmaxf(tm, sa[0][r]);
#pragma unroll
        for (int r = 0; r < 16; ++r) tm = fmaxf(tm, sa[1][r]);
        tm = fmaxf(tm, __shfl_xor(tm, 32, 64));

        if (!__all(tm <= mraw + 64.f)) {  // T13 defer-max
          float mnew = fmaxf(mraw, tm);
          float alpha = __builtin_exp2f((mraw - mnew) * C);
          lsum *= alpha;
#pragma unroll
          for (int r = 0; r < 16; ++r) { oacc[0][r] *= alpha; oacc[1][r] *= alpha; }
          mraw = mnew;
        }
        const float mC = mraw * C;
        float psum = 0.f;
#pragma unroll
        for (int t = 0; t < 2; ++t)
#pragma unroll
          for (int r = 0; r < 16; ++r) {
            float pp = __builtin_exp2f(__builtin_fmaf(sa[t][r], C, -mC));
            sa[t][r] = pp;
            psum += pp;
          }
        lsum += psum + __shfl_xor(psum, 32, 64);

        // ---- P^T -> bf16 B-frags (unconditional shfl + cndmask) + PV ----
        __builtin_amdgcn_s_setprio(1);
#pragma unroll
        for (int t = 0; t < 2; ++t) {
#pragma unroll
          for (int half = 0; half < 2; ++half) {
            const int rb = half * 8;
            unsigned a0 = pack2bf(sa[t][rb + 0], sa[t][rb + 1]);
            unsigned a1 = pack2bf(sa[t][rb + 2], sa[t][rb + 3]);
            unsigned b0w = pack2bf(sa[t][rb + 4], sa[t][rb + 5]);
            unsigned b1w = pack2bf(sa[t][rb + 6], sa[t][rb + 7]);
            unsigned xa0 = __shfl_xor(a0, 32, 64);
            unsigned xa1 = __shfl_xor(a1, 32, 64);
            unsigned xb0 = __shfl_xor(b0w, 32, 64);
            unsigned xb1 = __shfl_xor(b1w, 32, 64);
            union { unsigned u[4]; bf16x8 v; } pf;
            pf.u[0] = lo_half ? a0 : xb0;
            pf.u[1] = lo_half ? a1 : xb1;
            pf.u[2] = lo_half ? xa0 : b0w;
            pf.u[3] = lo_half ? xa1 : b1w;
            oacc[0] = __builtin_amdgcn_mfma_f32_32x32x16_bf16(
                vf[0][t * 2 + half], pf.v, oacc[0], 0, 0, 0);
            oacc[1] = __builtin_amdgcn_mfma_f32_32x32x16_bf16(
                vf[1][t * 2 + half], pf.v, oacc[1], 0, 0, 0);
          }
        }
        __builtin_amdgcn_s_setprio(0);
      }

      __syncthreads();  // stage complete + LDS reads done before overwrite
      buf ^= 1;
    }

    // ---- merge pair partials: pair1 publishes, pair0 merges + stores ----
    const int base = (wq * 64 + lane) * 37;  // stride-37: conflict-free
    if (p == 1) {
      scr[base + 0] = mraw;
      scr[base + 1] = lsum;
#pragma unroll
      for (int t = 0; t < 2; ++t)
#pragma unroll
        for (int r = 0; r < 16; ++r) scr[base + 2 + t * 16 + r] = oacc[t][r];
    }
    __syncthreads();
    if (p == 0) {
      const float mB = scr[base + 0], lB = scr[base + 1];
      const float mS = fmaxf(mraw, mB);
      const float aA = __builtin_exp2f((mraw - mS) * C);
      const float aB = __builtin_exp2f((mB - mS) * C);
      const float lT = lsum * aA + lB * aB;
      const float linv = 1.0f / lT;
      ushort* crow = &ctx[((size_t)(b * S_LEN) + qrow) * DMODEL + h * HDIM];
#pragma unroll
      for (int t = 0; t < 2; ++t)
#pragma unroll
        for (int g2 = 0; g2 < 4; ++g2) {
          ushort4 o;  // hd = t*32 + g2*8 + hi*4 + r
          float m0 = oacc[t][g2 * 4 + 0] * aA + scr[base + 2 + t * 16 + g2 * 4 + 0] * aB;
          float m1 = oacc[t][g2 * 4 + 1] * aA + scr[base + 2 + t * 16 + g2 * 4 + 1] * aB;
          float m2 = oacc[t][g2 * 4 + 2] * aA + scr[base + 2 + t * 16 + g2 * 4 + 2] * aB;
          float m3 = oacc[t][g2 * 4 + 3] * aA + scr[base + 2 + t * 16 + g2 * 4 + 3] * aB;
          o.x = f2bf(m0 * linv); o.y = f2bf(m1 * linv);
          o.z = f2bf(m2 * linv); o.w = f2bf(m3 * linv);
          *(ushort4*)&crow[t * 32 + g2 * 8 + hi * 4] = o;
        }
    }
    __syncthreads();  // scratch reads done before next phase restages LDS
  }
}

// ---------------- launch ----------------

extern "C" void kernel_launch(void* const* d_in, const int* in_sizes, int n_in,
                              void* d_out, int out_size, void* d_ws,
                              size_t ws_size, hipStream_t stream) {
  const float* x  = (const float*)d_in[0];
  const float* Wq = (const float*)d_in[1];
  const float* bq = (const float*)d_in[2];
  const float* Wk = (const float*)d_in[3];
  const float* bk = (const float*)d_in[4];
  const float* Wv = (const float*)d_in[5];
  const float* bv = (const float*)d_in[6];
  const float* Wo = (const float*)d_in[7];
  const float* bo = (const float*)d_in[8];

  char* ws = (char*)d_ws;
  ushort* Xbf = (ushort*)ws;                               // 8 MB
  ushort* WT  = (ushort*)(ws + (size_t)8 * 1024 * 1024);   // 8 MB
  ushort* QKV = (ushort*)(ws + (size_t)16 * 1024 * 1024);  // 24 MB
  ushort* CTX = (ushort*)(ws + (size_t)40 * 1024 * 1024);  // 8 MB

  const size_t QKV_ELEMS = (size_t)MROWS * DMODEL;
  const size_t W_ELEMS = (size_t)DMODEL * DMODEL;

  cvt_x<<<4096, 256, 0, stream>>>(x, Xbf);
  cvt_wt<<<dim3(32, 32, 4), 256, 0, stream>>>(Wq, Wk, Wv, Wo, WT);
  gemm256<<<dim3(16, 12), 512, 0, stream>>>(Xbf, WT, bq, bk, bv, QKV);
  attn4<<<dim3(512), 256, 0, stream>>>(QKV, QKV + QKV_ELEMS,
                                       QKV + 2 * QKV_ELEMS, CTX);
  gemm128o<<<dim3(32, 8), 256, 0, stream>>>(CTX, WT + 3 * W_ELEMS, bo,
                                            (float*)d_out);
}

// Round 11
// 126.894 us; speedup vs baseline: 1.1497x; 1.1497x over previous
//
#include <hip/hip_runtime.h>

// MHA: B=2, S=2048, D=1024, H=16, HD=64, causal, scale=1/8.
// Round 11: kill the Vt output scatter. gemm256 now writes Q,K,V all
// row-major [B,H,S,HD] (V into CTX scratch); new trV kernel does an
// LDS-tiled 32x32 transpose V->Vt. attn4 / gemm128o / converts unchanged.
//   ws layout (bytes):
//     [0,8M)    Xbf  : x as bf16 [4096,1024]
//     [8M,16M)  WT   : WqT,WkT,WvT,WoT bf16 [1024,1024] each ([N][K])
//     [16M,32M) Q,K  : [B,H,S,HD] bf16
//     [32M,40M) Vt   : [B,H,HD,S] bf16 (written by trV)
//     [40M,48M) CTX  : first V row-major [B,H,S,HD] (gemm256 out, consumed
//                      by trV), then attention output bf16 [B,S,D]

#define S_LEN 2048
#define DMODEL 1024
#define NHEAD 16
#define HDIM 64
#define MROWS 4096  // B*S

typedef __bf16 bf16x8 __attribute__((ext_vector_type(8)));
typedef float f32x4 __attribute__((ext_vector_type(4)));
typedef float f32x16 __attribute__((ext_vector_type(16)));

__device__ __forceinline__ ushort f2bf(float f) {
  union { float f; unsigned u; } v; v.f = f;
  unsigned r = v.u + 0x7fffu + ((v.u >> 16) & 1u);  // RNE
  return (ushort)(r >> 16);
}

__device__ __forceinline__ void gload_lds16(const ushort* g, ushort* l) {
  __builtin_amdgcn_global_load_lds(
      (const __attribute__((address_space(1))) void*)g,
      (__attribute__((address_space(3))) void*)l, 16, 0, 0);
}

// pack two f32 -> one dword of 2 bf16 (compiler emits v_cvt_pk_bf16_f32)
__device__ __forceinline__ unsigned pack2bf(float lo, float hi) {
  union { __bf16 h[2]; unsigned u; } t;
  t.h[0] = (__bf16)lo; t.h[1] = (__bf16)hi;
  return t.u;
}

// ---------------- conversion kernels ----------------

__global__ __launch_bounds__(256) void cvt_x(const float* __restrict__ x,
                                             ushort* __restrict__ xb) {
  int i = (blockIdx.x * 256 + threadIdx.x) * 4;
  float4 v = *(const float4*)&x[i];
  ushort4 o;
  o.x = f2bf(v.x); o.y = f2bf(v.y); o.z = f2bf(v.z); o.w = f2bf(v.w);
  *(ushort4*)&xb[i] = o;
}

// W [K][N] fp32 -> WT [N][K] bf16
__global__ __launch_bounds__(256) void cvt_wt(const float* __restrict__ W0,
                                              const float* __restrict__ W1,
                                              const float* __restrict__ W2,
                                              const float* __restrict__ W3,
                                              ushort* __restrict__ out) {
  const float* W = blockIdx.z == 0 ? W0 : blockIdx.z == 1 ? W1
                   : blockIdx.z == 2 ? W2 : W3;
  ushort* WT = out + (size_t)blockIdx.z * DMODEL * DMODEL;
  __shared__ float tile[32][33];
  int n0 = blockIdx.x * 32, k0 = blockIdx.y * 32;
  int tx = threadIdx.x & 31, ty = threadIdx.x >> 5;  // 32 x 8
#pragma unroll
  for (int i = 0; i < 32; i += 8)
    tile[ty + i][tx] = W[(size_t)(k0 + ty + i) * DMODEL + n0 + tx];
  __syncthreads();
#pragma unroll
  for (int i = 0; i < 32; i += 8)
    WT[(size_t)(n0 + ty + i) * DMODEL + k0 + tx] = f2bf(tile[tx][ty + i]);
}

// V [B,H,S,HD] -> Vt [B,H,HD,S], 32x32 LDS tiles
__global__ __launch_bounds__(256) void trV(const ushort* __restrict__ V,
                                           ushort* __restrict__ Vt) {
  const int bh = blockIdx.z;
  const ushort* src = V + (size_t)bh * S_LEN * HDIM;
  ushort* dst = Vt + (size_t)bh * HDIM * S_LEN;
  __shared__ ushort tile[32][33];
  int s0 = blockIdx.x * 32, h0 = blockIdx.y * 32;
  int tx = threadIdx.x & 31, ty = threadIdx.x >> 5;  // 32 x 8
#pragma unroll
  for (int i = 0; i < 32; i += 8)
    tile[ty + i][tx] = src[(size_t)(s0 + ty + i) * HDIM + h0 + tx];
  __syncthreads();
#pragma unroll
  for (int i = 0; i < 32; i += 8)
    dst[(size_t)(h0 + ty + i) * S_LEN + s0 + tx] = tile[tx][ty + i];
}

// ---------------- QKV GEMM: 256x256 tile, 8 waves, phase-paced ------------
// A = Xbf [4096,1024]; Bt = WT [3072 rows][1024] (QKV fused).
// Outputs: Q,K,V ALL row-major [B,H,S,HD] (V to scratch, transposed later).
__global__ __launch_bounds__(512) void gemm256(
    const ushort* __restrict__ A, const ushort* __restrict__ Bt,
    const float* __restrict__ b0, const float* __restrict__ b1,
    const float* __restrict__ b2, ushort* __restrict__ outQ,
    ushort* __restrict__ outK, ushort* __restrict__ outV) {
  const int flat = blockIdx.y * 16 + blockIdx.x;       // 0..191
  const int swz = (flat & 7) * 24 + (flat >> 3);       // bijective (192=8*24)
  const int bx = swz & 15, by = swz >> 4;
  const int m0 = bx * 256, n0 = by * 256;

  __shared__ __align__(16) ushort Al[2][256 * 64];  // 64 KB
  __shared__ __align__(16) ushort Bl[2][256 * 64];  // 64 KB

  const int tid = threadIdx.x;
  const int lane = tid & 63, wid = tid >> 6;
  const int wr = wid >> 2, wc = wid & 3;   // wave tile: rows wr*128, cols wc*64
  const int fr = lane & 15, hi16 = lane >> 4;

  f32x4 acc[8][4] = {};

  // ---- prologue: stage K-tile 0 into buf 0 (4 half-tiles) ----
#pragma unroll
  for (int htk = 0; htk < 4; ++htk) {
#pragma unroll
    for (int l = 0; l < 2; ++l) {
      int chunk = l * 512 + tid;               // 0..1023 within half-tile
      int row = chunk >> 3, cpos = chunk & 7;
      int scol = (cpos ^ (row & 7)) * 8;       // inverse-swizzled source col
      if (htk < 2)
        gload_lds16(&A[(size_t)(m0 + htk * 128 + row) * DMODEL + scol],
                    &Al[0][(htk * 1024 + chunk) * 8]);
      else
        gload_lds16(&Bt[(size_t)(n0 + (htk - 2) * 128 + row) * DMODEL + scol],
                    &Bl[0][((htk - 2) * 1024 + chunk) * 8]);
    }
  }
  __syncthreads();  // vmcnt drained: buf0 ready

  for (int t = 0; t < 16; ++t) {
    const int bt = t & 1;
    bf16x8 bfr[4];
#pragma unroll
    for (int s = 0; s < 4; ++s) {
      const int kk = s >> 1, mh = s & 1;
      // ds-read this sub-phase's register subtile (swizzled)
      bf16x8 af[4];
#pragma unroll
      for (int q = 0; q < 4; ++q) {
        int rl = wr * 128 + (mh * 4 + q) * 16 + fr;
        af[q] = *(const bf16x8*)&Al[bt][rl * 64 +
                                        ((kk * 4 + hi16) ^ (rl & 7)) * 8];
      }
      if (mh == 0) {
#pragma unroll
        for (int nf = 0; nf < 4; ++nf) {
          int rl = wc * 64 + nf * 16 + fr;
          bfr[nf] = *(const bf16x8*)&Bl[bt][rl * 64 +
                                            ((kk * 4 + hi16) ^ (rl & 7)) * 8];
        }
      }
      // stage ONE half-tile of K-tile t+1 into buf^1 (s: A-h0,A-h1,B-h0,B-h1)
      if (t + 1 < 16) {
        const int k64 = (t + 1) * 64;
#pragma unroll
        for (int l = 0; l < 2; ++l) {
          int chunk = l * 512 + tid;
          int row = chunk >> 3, cpos = chunk & 7;
          int scol = (cpos ^ (row & 7)) * 8;
          if (s < 2)
            gload_lds16(&A[(size_t)(m0 + s * 128 + row) * DMODEL + k64 + scol],
                        &Al[bt ^ 1][(s * 1024 + chunk) * 8]);
          else
            gload_lds16(
                &Bt[(size_t)(n0 + (s - 2) * 128 + row) * DMODEL + k64 + scol],
                &Bl[bt ^ 1][((s - 2) * 1024 + chunk) * 8]);
        }
      }
      __builtin_amdgcn_s_barrier();  // pacing: align waves into MFMA cluster
      __builtin_amdgcn_s_setprio(1);
#pragma unroll
      for (int q = 0; q < 4; ++q)
#pragma unroll
        for (int nf = 0; nf < 4; ++nf)
          acc[mh * 4 + q][nf] = __builtin_amdgcn_mfma_f32_16x16x32_bf16(
              af[q], bfr[nf], acc[mh * 4 + q][nf], 0, 0, 0);
      __builtin_amdgcn_s_setprio(0);
      if (s < 3) __builtin_amdgcn_s_barrier();
    }
    __syncthreads();  // buf bt reads done + tile t+1 stage drained (vmcnt 0)
  }

  // ---- epilogue: bias + row-major writes (NO scatter — V row-major) ----
#pragma unroll
  for (int mf = 0; mf < 8; ++mf) {
#pragma unroll
    for (int nf = 0; nf < 4; ++nf) {
      int col = n0 + wc * 64 + nf * 16 + fr;  // 0..3071
      int z = col >> 10, cw = col & 1023;
      float bval = z == 0 ? b0[cw] : z == 1 ? b1[cw] : b2[cw];
      int h = cw >> 6, hd = cw & (HDIM - 1);
      ushort* dst = (z == 0) ? outQ : (z == 1) ? outK : outV;
#pragma unroll
      for (int rg = 0; rg < 4; ++rg) {
        int row = m0 + wr * 128 + mf * 16 + hi16 * 4 + rg;
        int b = row >> 11, sq = row & (S_LEN - 1);
        float val = acc[mf][nf][rg] + bval;
        dst[(((size_t)(b * NHEAD + h)) * S_LEN + sq) * HDIM + hd] = f2bf(val);
      }
    }
  }
}

// ---------------- out-proj GEMM (128x128 tile, BK=64, 2-phase dbuf) -------
__global__ __launch_bounds__(256) void gemm128o(
    const ushort* __restrict__ A, const ushort* __restrict__ Bt,
    const float* __restrict__ b0, float* __restrict__ outB) {
  const int NT = 256;
  const int flat = blockIdx.y * 32 + blockIdx.x;
  const int swz = (flat & 7) * (NT >> 3) + (flat >> 3);
  const int bx = swz & 31, by = swz >> 5;
  const int m0 = bx * 128, n0 = by * 128;

  __shared__ __align__(16) ushort Alds[2][128 * 64];
  __shared__ __align__(16) ushort Blds[2][128 * 64];

  const int tid = threadIdx.x;
  const int lane = tid & 63, w = tid >> 6;
  const int wr = w >> 1, wc = w & 1;
  const int fr = lane & 15, hi16 = lane >> 4;

  f32x4 acc[4][4] = {};

  auto STAGE = [&](int kt, int bi) {
#pragma unroll
    for (int it = 0; it < 4; ++it) {
      int c = it * 256 + tid;
      int row = c >> 3;
      int sc = ((c & 7) ^ (row & 7)) * 8;
      int ldsbase = (it * 256 + w * 64) * 8;
      gload_lds16(&A[(size_t)(m0 + row) * DMODEL + kt + sc],
                  &Alds[bi][ldsbase]);
      gload_lds16(&Bt[(size_t)(n0 + row) * DMODEL + kt + sc],
                  &Blds[bi][ldsbase]);
    }
  };

  auto COMPUTE = [&](int bi) {
#pragma unroll
    for (int kk = 0; kk < 2; ++kk) {
      bf16x8 af[4], bfr[4];
#pragma unroll
      for (int i = 0; i < 4; ++i) {
        int row = wr * 64 + i * 16 + fr;
        af[i] = *(const bf16x8*)&Alds[bi][row * 64 +
                                          ((kk * 4 + hi16) ^ (row & 7)) * 8];
      }
#pragma unroll
      for (int j = 0; j < 4; ++j) {
        int row = wc * 64 + j * 16 + fr;
        bfr[j] = *(const bf16x8*)&Blds[bi][row * 64 +
                                           ((kk * 4 + hi16) ^ (row & 7)) * 8];
      }
#pragma unroll
      for (int i = 0; i < 4; ++i)
#pragma unroll
        for (int j = 0; j < 4; ++j)
          acc[i][j] = __builtin_amdgcn_mfma_f32_16x16x32_bf16(af[i], bfr[j],
                                                              acc[i][j], 0, 0, 0);
    }
  };

  STAGE(0, 0);
  __syncthreads();
  int buf = 0;
  for (int kt = 64; kt < DMODEL; kt += 64) {
    STAGE(kt, buf ^ 1);
    COMPUTE(buf);
    __syncthreads();
    buf ^= 1;
  }
  COMPUTE(buf);

#pragma unroll
  for (int i = 0; i < 4; ++i) {
#pragma unroll
    for (int j = 0; j < 4; ++j) {
      int col = n0 + wc * 64 + j * 16 + fr;
      float bval = b0[col];
#pragma unroll
      for (int r = 0; r < 4; ++r) {
        int row = m0 + wr * 64 + i * 16 + hi16 * 4 + r;
        outB[(size_t)row * DMODEL + col] = acc[i][j][r] + bval;
      }
    }
  }
}

// ---------------- flash attention (causal), split-KV 4-wave ----------------
// (unchanged from round 8)
__global__ __launch_bounds__(256, 2) void attn4(const ushort* __restrict__ Q,
                                                const ushort* __restrict__ K,
                                                const ushort* __restrict__ Vt,
                                                ushort* __restrict__ ctx) {
  const int n = blockIdx.x;
  const int v = (n & 7) * 64 + (n >> 3);  // bijective XCD-contiguous (512=8*64)
  const int ptile = v & 15, bh = v >> 4;
  const int b = bh >> 4, h = bh & 15;
  const int tid = threadIdx.x;
  const int lane = tid & 63, wid = tid >> 6;
  const int p = wid >> 1;        // KV-parity pair: 0 even steps, 1 odd
  const int wq = wid & 1;        // 32-row q-subtile within the 64-row tile
  const int q32 = lane & 31, hi = lane >> 5;
  const bool lo_half = (hi == 0);
  const int tid2 = tid & 127;    // pair-local thread id (2 waves = 128 thr)

  const ushort* Qb = Q + (size_t)bh * S_LEN * HDIM;
  const ushort* Kb = K + (size_t)bh * S_LEN * HDIM;
  const ushort* Vb = Vt + (size_t)bh * HDIM * S_LEN;

  __shared__ __align__(16) ushort Kl[2][2][64 * 64];  // [pair][buf] 32 KB
  __shared__ __align__(16) ushort Vl[2][2][64 * 64];  // 32 KB
  float* scr = (float*)&Kl[0][0][0];  // merge scratch overlay (post-loop only)

  const float C = 0.125f * 1.44269504f;  // scale * log2(e)

  for (int ph = 0; ph < 2; ++ph) {
    const int j = ph ? 31 - ptile : ptile;  // 64-row q-tile index, 0..31
    const int qbase = j * 64 + wq * 32;
    const int qrow = qbase + q32;

    bf16x8 qf[4];
#pragma unroll
    for (int s = 0; s < 4; ++s)
      qf[s] = *(const bf16x8*)&Qb[(size_t)qrow * HDIM + s * 16 + hi * 8];

    f32x16 oacc[2] = {};
    float mraw = -1e30f, lsum = 0.f;
    const int NS = (j >> 1) + 1;  // iterations (pair0 steps; pair1 <= this)

    // prologue: pair p stages its first step (s0 = p) into buf 0
    if (p <= j) {
      const int kv = p * 64;
#pragma unroll
      for (int it = 0; it < 4; ++it) {
        int chunk = it * 128 + tid2;
        int row = chunk >> 3, sc = ((chunk & 7) ^ (row & 7)) * 8;
        gload_lds16(&Kb[(size_t)(kv + row) * HDIM + sc], &Kl[p][0][chunk * 8]);
        gload_lds16(&Vb[(size_t)row * S_LEN + kv + sc], &Vl[p][0][chunk * 8]);
      }
    }
    __syncthreads();

    int buf = 0;
    for (int it = 0; it < NS; ++it) {
      const int s = 2 * it + p;      // my global KV step
      const int kv0 = s * 64;

      // issue my pair's next-tile stage (s+2) first — overlaps compute
      if (s + 2 <= j) {
        const int kvn = kv0 + 128;
#pragma unroll
        for (int st = 0; st < 4; ++st) {
          int chunk = st * 128 + tid2;
          int row = chunk >> 3, sc = ((chunk & 7) ^ (row & 7)) * 8;
          gload_lds16(&Kb[(size_t)(kvn + row) * HDIM + sc],
                      &Kl[p][buf ^ 1][chunk * 8]);
          gload_lds16(&Vb[(size_t)row * S_LEN + kvn + sc],
                      &Vl[p][buf ^ 1][chunk * 8]);
        }
      }

      if (s <= j) {
        // ---- QK^T: S^T[k][q], 2 tiles of 32 k ----
        f32x16 sa[2] = {};
        __builtin_amdgcn_s_setprio(1);
#pragma unroll
        for (int t = 0; t < 2; ++t) {
          const int row = t * 32 + q32;
          const int rsw = (row & 7);
#pragma unroll
          for (int sl = 0; sl < 4; ++sl) {
            bf16x8 kf = *(const bf16x8*)&Kl[p][buf][row * 64 +
                                                    ((sl * 2 + hi) ^ rsw) * 8];
            sa[t] = __builtin_amdgcn_mfma_f32_32x32x16_bf16(kf, qf[sl], sa[t],
                                                            0, 0, 0);
          }
        }
        __builtin_amdgcn_s_setprio(0);

        // ---- V^T A-frags from LDS ----
        bf16x8 vf[2][4];
#pragma unroll
        for (int t2 = 0; t2 < 2; ++t2) {
          const int row = t2 * 32 + q32;
          const int rsw = (row & 7);
#pragma unroll
          for (int sl = 0; sl < 4; ++sl)
            vf[t2][sl] = *(const bf16x8*)&Vl[p][buf][row * 64 +
                                                     ((sl * 2 + hi) ^ rsw) * 8];
        }

        // ---- causal mask (only step s == j masks; wave-uniform) ----
        if (kv0 + 63 > qbase) {
          const int khi = kv0 + 4 * hi;
#pragma unroll
          for (int t = 0; t < 2; ++t)
#pragma unroll
            for (int r = 0; r < 16; ++r) {
              int kg = khi + t * 32 + (r & 3) + 8 * (r >> 2);
              if (kg > qrow) sa[t][r] = -1e30f;
            }
        }

        // ---- online softmax (raw domain; lane-local rows) ----
        float tm = sa[0][0];
#pragma unroll
        for (int r = 1; r < 16; ++r) tm = fmaxf(tm, sa[0][r]);
#pragma unroll
        for (int r = 0; r < 16; ++r) tm = fmaxf(tm, sa[1][r]);
        tm = fmaxf(tm, __shfl_xor(tm, 32, 64));

        if (!__all(tm <= mraw + 64.f)) {  // T13 defer-max
          float mnew = fmaxf(mraw, tm);
          float alpha = __builtin_exp2f((mraw - mnew) * C);
          lsum *= alpha;
#pragma unroll
          for (int r = 0; r < 16; ++r) { oacc[0][r] *= alpha; oacc[1][r] *= alpha; }
          mraw = mnew;
        }
        const float mC = mraw * C;
        float psum = 0.f;
#pragma unroll
        for (int t = 0; t < 2; ++t)
#pragma unroll
          for (int r = 0; r < 16; ++r) {
            float pp = __builtin_exp2f(__builtin_fmaf(sa[t][r], C, -mC));
            sa[t][r] = pp;
            psum += pp;
          }
        lsum += psum + __shfl_xor(psum, 32, 64);

        // ---- P^T -> bf16 B-frags (unconditional shfl + cndmask) + PV ----
        __builtin_amdgcn_s_setprio(1);
#pragma unroll
        for (int t = 0; t < 2; ++t) {
#pragma unroll
          for (int half = 0; half < 2; ++half) {
            const int rb = half * 8;
            unsigned a0 = pack2bf(sa[t][rb + 0], sa[t][rb + 1]);
            unsigned a1 = pack2bf(sa[t][rb + 2], sa[t][rb + 3]);
            unsigned b0w = pack2bf(sa[t][rb + 4], sa[t][rb + 5]);
            unsigned b1w = pack2bf(sa[t][rb + 6], sa[t][rb + 7]);
            unsigned xa0 = __shfl_xor(a0, 32, 64);
            unsigned xa1 = __shfl_xor(a1, 32, 64);
            unsigned xb0 = __shfl_xor(b0w, 32, 64);
            unsigned xb1 = __shfl_xor(b1w, 32, 64);
            union { unsigned u[4]; bf16x8 v; } pf;
            pf.u[0] = lo_half ? a0 : xb0;
            pf.u[1] = lo_half ? a1 : xb1;
            pf.u[2] = lo_half ? xa0 : b0w;
            pf.u[3] = lo_half ? xa1 : b1w;
            oacc[0] = __builtin_amdgcn_mfma_f32_32x32x16_bf16(
                vf[0][t * 2 + half], pf.v, oacc[0], 0, 0, 0);
            oacc[1] = __builtin_amdgcn_mfma_f32_32x32x16_bf16(
                vf[1][t * 2 + half], pf.v, oacc[1], 0, 0, 0);
          }
        }
        __builtin_amdgcn_s_setprio(0);
      }

      __syncthreads();  // stage complete + LDS reads done before overwrite
      buf ^= 1;
    }

    // ---- merge pair partials: pair1 publishes, pair0 merges + stores ----
    const int base = (wq * 64 + lane) * 37;  // stride-37: conflict-free
    if (p == 1) {
      scr[base + 0] = mraw;
      scr[base + 1] = lsum;
#pragma unroll
      for (int t = 0; t < 2; ++t)
#pragma unroll
        for (int r = 0; r < 16; ++r) scr[base + 2 + t * 16 + r] = oacc[t][r];
    }
    __syncthreads();
    if (p == 0) {
      const float mB = scr[base + 0], lB = scr[base + 1];
      const float mS = fmaxf(mraw, mB);
      const float aA = __builtin_exp2f((mraw - mS) * C);
      const float aB = __builtin_exp2f((mB - mS) * C);
      const float lT = lsum * aA + lB * aB;
      const float linv = 1.0f / lT;
      ushort* crow = &ctx[((size_t)(b * S_LEN) + qrow) * DMODEL + h * HDIM];
#pragma unroll
      for (int t = 0; t < 2; ++t)
#pragma unroll
        for (int g2 = 0; g2 < 4; ++g2) {
          ushort4 o;  // hd = t*32 + g2*8 + hi*4 + r
          float m0 = oacc[t][g2 * 4 + 0] * aA + scr[base + 2 + t * 16 + g2 * 4 + 0] * aB;
          float m1 = oacc[t][g2 * 4 + 1] * aA + scr[base + 2 + t * 16 + g2 * 4 + 1] * aB;
          float m2 = oacc[t][g2 * 4 + 2] * aA + scr[base + 2 + t * 16 + g2 * 4 + 2] * aB;
          float m3 = oacc[t][g2 * 4 + 3] * aA + scr[base + 2 + t * 16 + g2 * 4 + 3] * aB;
          o.x = f2bf(m0 * linv); o.y = f2bf(m1 * linv);
          o.z = f2bf(m2 * linv); o.w = f2bf(m3 * linv);
          *(ushort4*)&crow[t * 32 + g2 * 8 + hi * 4] = o;
        }
    }
    __syncthreads();  // scratch reads done before next phase restages LDS
  }
}

// ---------------- launch ----------------

extern "C" void kernel_launch(void* const* d_in, const int* in_sizes, int n_in,
                              void* d_out, int out_size, void* d_ws,
                              size_t ws_size, hipStream_t stream) {
  const float* x  = (const float*)d_in[0];
  const float* Wq = (const float*)d_in[1];
  const float* bq = (const float*)d_in[2];
  const float* Wk = (const float*)d_in[3];
  const float* bk = (const float*)d_in[4];
  const float* Wv = (const float*)d_in[5];
  const float* bv = (const float*)d_in[6];
  const float* Wo = (const float*)d_in[7];
  const float* bo = (const float*)d_in[8];

  char* ws = (char*)d_ws;
  ushort* Xbf = (ushort*)ws;                               // 8 MB
  ushort* WT  = (ushort*)(ws + (size_t)8 * 1024 * 1024);   // 8 MB
  ushort* QKV = (ushort*)(ws + (size_t)16 * 1024 * 1024);  // Q,K then Vt
  ushort* CTX = (ushort*)(ws + (size_t)40 * 1024 * 1024);  // V-rowmajor, ctx

  const size_t QKV_ELEMS = (size_t)MROWS * DMODEL;  // 4 M elems = 8 MB
  const size_t W_ELEMS = (size_t)DMODEL * DMODEL;

  ushort* Qp  = QKV;                  // [B,H,S,HD]
  ushort* Kp  = QKV + QKV_ELEMS;      // [B,H,S,HD]
  ushort* Vtp = QKV + 2 * QKV_ELEMS;  // [B,H,HD,S]  (trV output)
  ushort* Vrp = CTX;                  // [B,H,S,HD]  (gemm256 scratch out)

  cvt_x<<<4096, 256, 0, stream>>>(x, Xbf);
  cvt_wt<<<dim3(32, 32, 4), 256, 0, stream>>>(Wq, Wk, Wv, Wo, WT);
  gemm256<<<dim3(16, 12), 512, 0, stream>>>(Xbf, WT, bq, bk, bv, Qp, Kp, Vrp);
  trV<<<dim3(64, 2, 32), 256, 0, stream>>>(Vrp, Vtp);
  attn4<<<dim3(512), 256, 0, stream>>>(Qp, Kp, Vtp, CTX);
  gemm128o<<<dim3(32, 8), 256, 0, stream>>>(CTX, WT + 3 * W_ELEMS, bo,
                                            (float*)d_out);
}

// Round 12
// 126.686 us; speedup vs baseline: 1.1515x; 1.0016x over previous
//
#include <hip/hip_runtime.h>

// MHA: B=2, S=2048, D=1024, H=16, HD=64, causal, scale=1/8.
// Round 12: (a) gemm256 — stage ALL of K-tile t+1 during sub-phases 0..1
// (A then B), so the tile-end vmcnt(0) drain hits loads >=2 sub-phases old
// (~zero stall). (b) attn4 — v_permlane32_swap (builtin, shfl fallback)
// replaces 16 bpermute+16 cndmask in P-redistribution and the max/sum
// half-combines; fmax tree. Everything else identical to round 11.
//   ws layout (bytes):
//     [0,8M)    Xbf  : x as bf16 [4096,1024]
//     [8M,16M)  WT   : WqT,WkT,WvT,WoT bf16 [1024,1024] each ([N][K])
//     [16M,32M) Q,K  : [B,H,S,HD] bf16
//     [32M,40M) Vt   : [B,H,HD,S] bf16 (written by trV)
//     [40M,48M) CTX  : first V row-major (gemm256 out), then ctx [B,S,D]

#define S_LEN 2048
#define DMODEL 1024
#define NHEAD 16
#define HDIM 64
#define MROWS 4096  // B*S

typedef __bf16 bf16x8 __attribute__((ext_vector_type(8)));
typedef float f32x4 __attribute__((ext_vector_type(4)));
typedef float f32x16 __attribute__((ext_vector_type(16)));

__device__ __forceinline__ ushort f2bf(float f) {
  union { float f; unsigned u; } v; v.f = f;
  unsigned r = v.u + 0x7fffu + ((v.u >> 16) & 1u);  // RNE
  return (ushort)(r >> 16);
}

__device__ __forceinline__ void gload_lds16(const ushort* g, ushort* l) {
  __builtin_amdgcn_global_load_lds(
      (const __attribute__((address_space(1))) void*)g,
      (__attribute__((address_space(3))) void*)l, 16, 0, 0);
}

// pack two f32 -> one dword of 2 bf16 (compiler emits v_cvt_pk_bf16_f32)
__device__ __forceinline__ unsigned pack2bf(float lo, float hi) {
  union { __bf16 h[2]; unsigned u; } t;
  t.h[0] = (__bf16)lo; t.h[1] = (__bf16)hi;
  return t.u;
}

#if __has_builtin(__builtin_amdgcn_permlane32_swap)
#define HAVE_PL32 1
// after call: a = {a.lo | b.lo}, b = {a.hi | b.hi}  (lane<32 | lane>=32)
__device__ __forceinline__ void pl32sw(unsigned& a, unsigned& b) {
  auto r = __builtin_amdgcn_permlane32_swap((int)a, (int)b, false, false);
  a = (unsigned)r[0];
  b = (unsigned)r[1];
}
#endif

__device__ __forceinline__ float halfcomb_max(float x) {
#ifdef HAVE_PL32
  unsigned a = __float_as_uint(x), b = a;
  pl32sw(a, b);
  return fmaxf(__uint_as_float(a), __uint_as_float(b));
#else
  return fmaxf(x, __shfl_xor(x, 32, 64));
#endif
}
__device__ __forceinline__ float halfcomb_sum(float x) {
#ifdef HAVE_PL32
  unsigned a = __float_as_uint(x), b = a;
  pl32sw(a, b);
  return __uint_as_float(a) + __uint_as_float(b);
#else
  return x + __shfl_xor(x, 32, 64);
#endif
}

// ---------------- conversion kernels ----------------

__global__ __launch_bounds__(256) void cvt_x(const float* __restrict__ x,
                                             ushort* __restrict__ xb) {
  int i = (blockIdx.x * 256 + threadIdx.x) * 4;
  float4 v = *(const float4*)&x[i];
  ushort4 o;
  o.x = f2bf(v.x); o.y = f2bf(v.y); o.z = f2bf(v.z); o.w = f2bf(v.w);
  *(ushort4*)&xb[i] = o;
}

// W [K][N] fp32 -> WT [N][K] bf16
__global__ __launch_bounds__(256) void cvt_wt(const float* __restrict__ W0,
                                              const float* __restrict__ W1,
                                              const float* __restrict__ W2,
                                              const float* __restrict__ W3,
                                              ushort* __restrict__ out) {
  const float* W = blockIdx.z == 0 ? W0 : blockIdx.z == 1 ? W1
                   : blockIdx.z == 2 ? W2 : W3;
  ushort* WT = out + (size_t)blockIdx.z * DMODEL * DMODEL;
  __shared__ float tile[32][33];
  int n0 = blockIdx.x * 32, k0 = blockIdx.y * 32;
  int tx = threadIdx.x & 31, ty = threadIdx.x >> 5;  // 32 x 8
#pragma unroll
  for (int i = 0; i < 32; i += 8)
    tile[ty + i][tx] = W[(size_t)(k0 + ty + i) * DMODEL + n0 + tx];
  __syncthreads();
#pragma unroll
  for (int i = 0; i < 32; i += 8)
    WT[(size_t)(n0 + ty + i) * DMODEL + k0 + tx] = f2bf(tile[tx][ty + i]);
}

// V [B,H,S,HD] -> Vt [B,H,HD,S], 32x32 LDS tiles
__global__ __launch_bounds__(256) void trV(const ushort* __restrict__ V,
                                           ushort* __restrict__ Vt) {
  const int bh = blockIdx.z;
  const ushort* src = V + (size_t)bh * S_LEN * HDIM;
  ushort* dst = Vt + (size_t)bh * HDIM * S_LEN;
  __shared__ ushort tile[32][33];
  int s0 = blockIdx.x * 32, h0 = blockIdx.y * 32;
  int tx = threadIdx.x & 31, ty = threadIdx.x >> 5;  // 32 x 8
#pragma unroll
  for (int i = 0; i < 32; i += 8)
    tile[ty + i][tx] = src[(size_t)(s0 + ty + i) * HDIM + h0 + tx];
  __syncthreads();
#pragma unroll
  for (int i = 0; i < 32; i += 8)
    dst[(size_t)(h0 + ty + i) * S_LEN + s0 + tx] = tile[tx][ty + i];
}

// ---------------- QKV GEMM: 256x256 tile, 8 waves, phase-paced ------------
// A = Xbf [4096,1024]; Bt = WT [3072 rows][1024] (QKV fused).
// Outputs: Q,K,V ALL row-major [B,H,S,HD] (V to scratch, transposed later).
__global__ __launch_bounds__(512) void gemm256(
    const ushort* __restrict__ A, const ushort* __restrict__ Bt,
    const float* __restrict__ b0, const float* __restrict__ b1,
    const float* __restrict__ b2, ushort* __restrict__ outQ,
    ushort* __restrict__ outK, ushort* __restrict__ outV) {
  const int flat = blockIdx.y * 16 + blockIdx.x;       // 0..191
  const int swz = (flat & 7) * 24 + (flat >> 3);       // bijective (192=8*24)
  const int bx = swz & 15, by = swz >> 4;
  const int m0 = bx * 256, n0 = by * 256;

  __shared__ __align__(16) ushort Al[2][256 * 64];  // 64 KB
  __shared__ __align__(16) ushort Bl[2][256 * 64];  // 64 KB

  const int tid = threadIdx.x;
  const int lane = tid & 63, wid = tid >> 6;
  const int wr = wid >> 2, wc = wid & 3;   // wave tile: rows wr*128, cols wc*64
  const int fr = lane & 15, hi16 = lane >> 4;

  f32x4 acc[8][4] = {};

  // ---- prologue: stage K-tile 0 into buf 0 (full 256x64 A and B) ----
#pragma unroll
  for (int l = 0; l < 4; ++l) {
    int chunk = l * 512 + tid;               // 0..2047 over 256x64 tile
    int row = chunk >> 3, cpos = chunk & 7;
    int scol = (cpos ^ (row & 7)) * 8;       // inverse-swizzled source col
    gload_lds16(&A[(size_t)(m0 + row) * DMODEL + scol], &Al[0][chunk * 8]);
    gload_lds16(&Bt[(size_t)(n0 + row) * DMODEL + scol], &Bl[0][chunk * 8]);
  }
  __syncthreads();  // vmcnt drained: buf0 ready

  for (int t = 0; t < 16; ++t) {
    const int bt = t & 1;
    bf16x8 bfr[4];
#pragma unroll
    for (int s = 0; s < 4; ++s) {
      const int kk = s >> 1, mh = s & 1;
      // ds-read this sub-phase's register subtile (swizzled)
      bf16x8 af[4];
#pragma unroll
      for (int q = 0; q < 4; ++q) {
        int rl = wr * 128 + (mh * 4 + q) * 16 + fr;
        af[q] = *(const bf16x8*)&Al[bt][rl * 64 +
                                        ((kk * 4 + hi16) ^ (rl & 7)) * 8];
      }
      if (mh == 0) {
#pragma unroll
        for (int nf = 0; nf < 4; ++nf) {
          int rl = wc * 64 + nf * 16 + fr;
          bfr[nf] = *(const bf16x8*)&Bl[bt][rl * 64 +
                                            ((kk * 4 + hi16) ^ (rl & 7)) * 8];
        }
      }
      // stage K-tile t+1 EARLY: full A tile at s=0, full B tile at s=1.
      // Earliest consumption is 3 sub-phases later, so the tile-end
      // vmcnt(0) drain hits loads that are long complete.
      if (t + 1 < 16 && s < 2) {
        const int k64 = (t + 1) * 64;
#pragma unroll
        for (int l = 0; l < 4; ++l) {
          int chunk = l * 512 + tid;           // 0..2047
          int row = chunk >> 3, cpos = chunk & 7;
          int scol = (cpos ^ (row & 7)) * 8;
          if (s == 0)
            gload_lds16(&A[(size_t)(m0 + row) * DMODEL + k64 + scol],
                        &Al[bt ^ 1][chunk * 8]);
          else
            gload_lds16(&Bt[(size_t)(n0 + row) * DMODEL + k64 + scol],
                        &Bl[bt ^ 1][chunk * 8]);
        }
      }
      __builtin_amdgcn_s_barrier();  // pacing: align waves into MFMA cluster
      __builtin_amdgcn_s_setprio(1);
#pragma unroll
      for (int q = 0; q < 4; ++q)
#pragma unroll
        for (int nf = 0; nf < 4; ++nf)
          acc[mh * 4 + q][nf] = __builtin_amdgcn_mfma_f32_16x16x32_bf16(
              af[q], bfr[nf], acc[mh * 4 + q][nf], 0, 0, 0);
      __builtin_amdgcn_s_setprio(0);
      if (s < 3) __builtin_amdgcn_s_barrier();
    }
    __syncthreads();  // buf bt reads done + tile t+1 stage drained
  }

  // ---- epilogue: bias + row-major writes ----
#pragma unroll
  for (int mf = 0; mf < 8; ++mf) {
#pragma unroll
    for (int nf = 0; nf < 4; ++nf) {
      int col = n0 + wc * 64 + nf * 16 + fr;  // 0..3071
      int z = col >> 10, cw = col & 1023;
      float bval = z == 0 ? b0[cw] : z == 1 ? b1[cw] : b2[cw];
      int h = cw >> 6, hd = cw & (HDIM - 1);
      ushort* dst = (z == 0) ? outQ : (z == 1) ? outK : outV;
#pragma unroll
      for (int rg = 0; rg < 4; ++rg) {
        int row = m0 + wr * 128 + mf * 16 + hi16 * 4 + rg;
        int b = row >> 11, sq = row & (S_LEN - 1);
        float val = acc[mf][nf][rg] + bval;
        dst[(((size_t)(b * NHEAD + h)) * S_LEN + sq) * HDIM + hd] = f2bf(val);
      }
    }
  }
}

// ---------------- out-proj GEMM (128x128 tile, BK=64, 2-phase dbuf) -------
__global__ __launch_bounds__(256) void gemm128o(
    const ushort* __restrict__ A, const ushort* __restrict__ Bt,
    const float* __restrict__ b0, float* __restrict__ outB) {
  const int NT = 256;
  const int flat = blockIdx.y * 32 + blockIdx.x;
  const int swz = (flat & 7) * (NT >> 3) + (flat >> 3);
  const int bx = swz & 31, by = swz >> 5;
  const int m0 = bx * 128, n0 = by * 128;

  __shared__ __align__(16) ushort Alds[2][128 * 64];
  __shared__ __align__(16) ushort Blds[2][128 * 64];

  const int tid = threadIdx.x;
  const int lane = tid & 63, w = tid >> 6;
  const int wr = w >> 1, wc = w & 1;
  const int fr = lane & 15, hi16 = lane >> 4;

  f32x4 acc[4][4] = {};

  auto STAGE = [&](int kt, int bi) {
#pragma unroll
    for (int it = 0; it < 4; ++it) {
      int c = it * 256 + tid;
      int row = c >> 3;
      int sc = ((c & 7) ^ (row & 7)) * 8;
      int ldsbase = (it * 256 + w * 64) * 8;
      gload_lds16(&A[(size_t)(m0 + row) * DMODEL + kt + sc],
                  &Alds[bi][ldsbase]);
      gload_lds16(&Bt[(size_t)(n0 + row) * DMODEL + kt + sc],
                  &Blds[bi][ldsbase]);
    }
  };

  auto COMPUTE = [&](int bi) {
#pragma unroll
    for (int kk = 0; kk < 2; ++kk) {
      bf16x8 af[4], bfr[4];
#pragma unroll
      for (int i = 0; i < 4; ++i) {
        int row = wr * 64 + i * 16 + fr;
        af[i] = *(const bf16x8*)&Alds[bi][row * 64 +
                                          ((kk * 4 + hi16) ^ (row & 7)) * 8];
      }
#pragma unroll
      for (int j = 0; j < 4; ++j) {
        int row = wc * 64 + j * 16 + fr;
        bfr[j] = *(const bf16x8*)&Blds[bi][row * 64 +
                                           ((kk * 4 + hi16) ^ (row & 7)) * 8];
      }
#pragma unroll
      for (int i = 0; i < 4; ++i)
#pragma unroll
        for (int j = 0; j < 4; ++j)
          acc[i][j] = __builtin_amdgcn_mfma_f32_16x16x32_bf16(af[i], bfr[j],
                                                              acc[i][j], 0, 0, 0);
    }
  };

  STAGE(0, 0);
  __syncthreads();
  int buf = 0;
  for (int kt = 64; kt < DMODEL; kt += 64) {
    STAGE(kt, buf ^ 1);
    COMPUTE(buf);
    __syncthreads();
    buf ^= 1;
  }
  COMPUTE(buf);

#pragma unroll
  for (int i = 0; i < 4; ++i) {
#pragma unroll
    for (int j = 0; j < 4; ++j) {
      int col = n0 + wc * 64 + j * 16 + fr;
      float bval = b0[col];
#pragma unroll
      for (int r = 0; r < 4; ++r) {
        int row = m0 + wr * 64 + i * 16 + hi16 * 4 + r;
        outB[(size_t)row * DMODEL + col] = acc[i][j][r] + bval;
      }
    }
  }
}

// ---------------- flash attention (causal), split-KV 4-wave ----------------
__global__ __launch_bounds__(256, 2) void attn4(const ushort* __restrict__ Q,
                                                const ushort* __restrict__ K,
                                                const ushort* __restrict__ Vt,
                                                ushort* __restrict__ ctx) {
  const int n = blockIdx.x;
  const int v = (n & 7) * 64 + (n >> 3);  // bijective XCD-contiguous (512=8*64)
  const int ptile = v & 15, bh = v >> 4;
  const int b = bh >> 4, h = bh & 15;
  const int tid = threadIdx.x;
  const int lane = tid & 63, wid = tid >> 6;
  const int p = wid >> 1;        // KV-parity pair: 0 even steps, 1 odd
  const int wq = wid & 1;        // 32-row q-subtile within the 64-row tile
  const int q32 = lane & 31, hi = lane >> 5;
  const bool lo_half = (hi == 0);
  const int tid2 = tid & 127;    // pair-local thread id (2 waves = 128 thr)

  const ushort* Qb = Q + (size_t)bh * S_LEN * HDIM;
  const ushort* Kb = K + (size_t)bh * S_LEN * HDIM;
  const ushort* Vb = Vt + (size_t)bh * HDIM * S_LEN;

  __shared__ __align__(16) ushort Kl[2][2][64 * 64];  // [pair][buf] 32 KB
  __shared__ __align__(16) ushort Vl[2][2][64 * 64];  // 32 KB
  float* scr = (float*)&Kl[0][0][0];  // merge scratch overlay (post-loop only)

  const float C = 0.125f * 1.44269504f;  // scale * log2(e)

  for (int ph = 0; ph < 2; ++ph) {
    const int j = ph ? 31 - ptile : ptile;  // 64-row q-tile index, 0..31
    const int qbase = j * 64 + wq * 32;
    const int qrow = qbase + q32;

    bf16x8 qf[4];
#pragma unroll
    for (int s = 0; s < 4; ++s)
      qf[s] = *(const bf16x8*)&Qb[(size_t)qrow * HDIM + s * 16 + hi * 8];

    f32x16 oacc[2] = {};
    float mraw = -1e30f, lsum = 0.f;
    const int NS = (j >> 1) + 1;  // iterations (pair0 steps; pair1 <= this)

    // prologue: pair p stages its first step (s0 = p) into buf 0
    if (p <= j) {
      const int kv = p * 64;
#pragma unroll
      for (int it = 0; it < 4; ++it) {
        int chunk = it * 128 + tid2;
        int row = chunk >> 3, sc = ((chunk & 7) ^ (row & 7)) * 8;
        gload_lds16(&Kb[(size_t)(kv + row) * HDIM + sc], &Kl[p][0][chunk * 8]);
        gload_lds16(&Vb[(size_t)row * S_LEN + kv + sc], &Vl[p][0][chunk * 8]);
      }
    }
    __syncthreads();

    int buf = 0;
    for (int it = 0; it < NS; ++it) {
      const int s = 2 * it + p;      // my global KV step
      const int kv0 = s * 64;

      // issue my pair's next-tile stage (s+2) first — overlaps compute
      if (s + 2 <= j) {
        const int kvn = kv0 + 128;
#pragma unroll
        for (int st = 0; st < 4; ++st) {
          int chunk = st * 128 + tid2;
          int row = chunk >> 3, sc = ((chunk & 7) ^ (row & 7)) * 8;
          gload_lds16(&Kb[(size_t)(kvn + row) * HDIM + sc],
                      &Kl[p][buf ^ 1][chunk * 8]);
          gload_lds16(&Vb[(size_t)row * S_LEN + kvn + sc],
                      &Vl[p][buf ^ 1][chunk * 8]);
        }
      }

      if (s <= j) {
        // ---- QK^T: S^T[k][q], 2 tiles of 32 k ----
        f32x16 sa[2] = {};
        __builtin_amdgcn_s_setprio(1);
#pragma unroll
        for (int t = 0; t < 2; ++t) {
          const int row = t * 32 + q32;
          const int rsw = (row & 7);
#pragma unroll
          for (int sl = 0; sl < 4; ++sl) {
            bf16x8 kf = *(const bf16x8*)&Kl[p][buf][row * 64 +
                                                    ((sl * 2 + hi) ^ rsw) * 8];
            sa[t] = __builtin_amdgcn_mfma_f32_32x32x16_bf16(kf, qf[sl], sa[t],
                                                            0, 0, 0);
          }
        }
        __builtin_amdgcn_s_setprio(0);

        // ---- V^T A-frags from LDS ----
        bf16x8 vf[2][4];
#pragma unroll
        for (int t2 = 0; t2 < 2; ++t2) {
          const int row = t2 * 32 + q32;
          const int rsw = (row & 7);
#pragma unroll
          for (int sl = 0; sl < 4; ++sl)
            vf[t2][sl] = *(const bf16x8*)&Vl[p][buf][row * 64 +
                                                     ((sl * 2 + hi) ^ rsw) * 8];
        }

        // ---- causal mask (only step s == j masks; wave-uniform) ----
        if (kv0 + 63 > qbase) {
          const int khi = kv0 + 4 * hi;
#pragma unroll
          for (int t = 0; t < 2; ++t)
#pragma unroll
            for (int r = 0; r < 16; ++r) {
              int kg = khi + t * 32 + (r & 3) + 8 * (r >> 2);
              if (kg > qrow) sa[t][r] = -1e30f;
            }
        }

        // ---- online softmax (raw domain; lane-local rows) ----
        float tmv[8];
#pragma unroll
        for (int r = 0; r < 8; ++r)
          tmv[r] = fmaxf(fmaxf(sa[0][r], sa[0][r + 8]),
                         fmaxf(sa[1][r], sa[1][r + 8]));
        float t0 = fmaxf(fmaxf(tmv[0], tmv[1]), fmaxf(tmv[2], tmv[3]));
        float t1 = fmaxf(fmaxf(tmv[4], tmv[5]), fmaxf(tmv[6], tmv[7]));
        float tm = halfcomb_max(fmaxf(t0, t1));

        if (!__all(tm <= mraw + 64.f)) {  // T13 defer-max
          float mnew = fmaxf(mraw, tm);
          float alpha = __builtin_exp2f((mraw - mnew) * C);
          lsum *= alpha;
#pragma unroll
          for (int r = 0; r < 16; ++r) { oacc[0][r] *= alpha; oacc[1][r] *= alpha; }
          mraw = mnew;
        }
        const float mC = mraw * C;
        float psum = 0.f;
#pragma unroll
        for (int t = 0; t < 2; ++t)
#pragma unroll
          for (int r = 0; r < 16; ++r) {
            float pp = __builtin_exp2f(__builtin_fmaf(sa[t][r], C, -mC));
            sa[t][r] = pp;
            psum += pp;
          }
        lsum += halfcomb_sum(psum);

        // ---- P^T -> bf16 B-frags + PV ----
        // permlane32_swap(a,b): a'={a.lo|b.lo}, b'={a.hi|b.hi} — exactly
        // pf.u[0]/pf.u[2] (and u[1]/u[3]) of the verified shfl+cndmask map.
        __builtin_amdgcn_s_setprio(1);
#pragma unroll
        for (int t = 0; t < 2; ++t) {
#pragma unroll
          for (int half = 0; half < 2; ++half) {
            const int rb = half * 8;
            unsigned a0 = pack2bf(sa[t][rb + 0], sa[t][rb + 1]);
            unsigned a1 = pack2bf(sa[t][rb + 2], sa[t][rb + 3]);
            unsigned b0w = pack2bf(sa[t][rb + 4], sa[t][rb + 5]);
            unsigned b1w = pack2bf(sa[t][rb + 6], sa[t][rb + 7]);
            union { unsigned u[4]; bf16x8 v; } pf;
#ifdef HAVE_PL32
            pl32sw(a0, b0w);
            pl32sw(a1, b1w);
            pf.u[0] = a0; pf.u[1] = a1; pf.u[2] = b0w; pf.u[3] = b1w;
#else
            unsigned xa0 = __shfl_xor(a0, 32, 64);
            unsigned xa1 = __shfl_xor(a1, 32, 64);
            unsigned xb0 = __shfl_xor(b0w, 32, 64);
            unsigned xb1 = __shfl_xor(b1w, 32, 64);
            pf.u[0] = lo_half ? a0 : xb0;
            pf.u[1] = lo_half ? a1 : xb1;
            pf.u[2] = lo_half ? xa0 : b0w;
            pf.u[3] = lo_half ? xa1 : b1w;
#endif
            oacc[0] = __builtin_amdgcn_mfma_f32_32x32x16_bf16(
                vf[0][t * 2 + half], pf.v, oacc[0], 0, 0, 0);
            oacc[1] = __builtin_amdgcn_mfma_f32_32x32x16_bf16(
                vf[1][t * 2 + half], pf.v, oacc[1], 0, 0, 0);
          }
        }
        __builtin_amdgcn_s_setprio(0);
      }

      __syncthreads();  // stage complete + LDS reads done before overwrite
      buf ^= 1;
    }

    // ---- merge pair partials: pair1 publishes, pair0 merges + stores ----
    const int base = (wq * 64 + lane) * 37;  // stride-37: conflict-free
    if (p == 1) {
      scr[base + 0] = mraw;
      scr[base + 1] = lsum;
#pragma unroll
      for (int t = 0; t < 2; ++t)
#pragma unroll
        for (int r = 0; r < 16; ++r) scr[base + 2 + t * 16 + r] = oacc[t][r];
    }
    __syncthreads();
    if (p == 0) {
      const float mB = scr[base + 0], lB = scr[base + 1];
      const float mS = fmaxf(mraw, mB);
      const float aA = __builtin_exp2f((mraw - mS) * C);
      const float aB = __builtin_exp2f((mB - mS) * C);
      const float lT = lsum * aA + lB * aB;
      const float linv = 1.0f / lT;
      ushort* crow = &ctx[((size_t)(b * S_LEN) + qrow) * DMODEL + h * HDIM];
#pragma unroll
      for (int t = 0; t < 2; ++t)
#pragma unroll
        for (int g2 = 0; g2 < 4; ++g2) {
          ushort4 o;  // hd = t*32 + g2*8 + hi*4 + r
          float m0 = oacc[t][g2 * 4 + 0] * aA + scr[base + 2 + t * 16 + g2 * 4 + 0] * aB;
          float m1 = oacc[t][g2 * 4 + 1] * aA + scr[base + 2 + t * 16 + g2 * 4 + 1] * aB;
          float m2 = oacc[t][g2 * 4 + 2] * aA + scr[base + 2 + t * 16 + g2 * 4 + 2] * aB;
          float m3 = oacc[t][g2 * 4 + 3] * aA + scr[base + 2 + t * 16 + g2 * 4 + 3] * aB;
          o.x = f2bf(m0 * linv); o.y = f2bf(m1 * linv);
          o.z = f2bf(m2 * linv); o.w = f2bf(m3 * linv);
          *(ushort4*)&crow[t * 32 + g2 * 8 + hi * 4] = o;
        }
    }
    __syncthreads();  // scratch reads done before next phase restages LDS
  }
}

// ---------------- launch ----------------

extern "C" void kernel_launch(void* const* d_in, const int* in_sizes, int n_in,
                              void* d_out, int out_size, void* d_ws,
                              size_t ws_size, hipStream_t stream) {
  const float* x  = (const float*)d_in[0];
  const float* Wq = (const float*)d_in[1];
  const float* bq = (const float*)d_in[2];
  const float* Wk = (const float*)d_in[3];
  const float* bk = (const float*)d_in[4];
  const float* Wv = (const float*)d_in[5];
  const float* bv = (const float*)d_in[6];
  const float* Wo = (const float*)d_in[7];
  const float* bo = (const float*)d_in[8];

  char* ws = (char*)d_ws;
  ushort* Xbf = (ushort*)ws;                               // 8 MB
  ushort* WT  = (ushort*)(ws + (size_t)8 * 1024 * 1024);   // 8 MB
  ushort* QKV = (ushort*)(ws + (size_t)16 * 1024 * 1024);  // Q,K then Vt
  ushort* CTX = (ushort*)(ws + (size_t)40 * 1024 * 1024);  // V-rowmajor, ctx

  const size_t QKV_ELEMS = (size_t)MROWS * DMODEL;  // 4 M elems = 8 MB
  const size_t W_ELEMS = (size_t)DMODEL * DMODEL;

  ushort* Qp  = QKV;                  // [B,H,S,HD]
  ushort* Kp  = QKV + QKV_ELEMS;      // [B,H,S,HD]
  ushort* Vtp = QKV + 2 * QKV_ELEMS;  // [B,H,HD,S]  (trV output)
  ushort* Vrp = CTX;                  // [B,H,S,HD]  (gemm256 scratch out)

  cvt_x<<<4096, 256, 0, stream>>>(x, Xbf);
  cvt_wt<<<dim3(32, 32, 4), 256, 0, stream>>>(Wq, Wk, Wv, Wo, WT);
  gemm256<<<dim3(16, 12), 512, 0, stream>>>(Xbf, WT, bq, bk, bv, Qp, Kp, Vrp);
  trV<<<dim3(64, 2, 32), 256, 0, stream>>>(Vrp, Vtp);
  attn4<<<dim3(512), 256, 0, stream>>>(Qp, Kp, Vtp, CTX);
  gemm128o<<<dim3(32, 8), 256, 0, stream>>>(CTX, WT + 3 * W_ELEMS, bo,
                                            (float*)d_out);
}

// Round 13
// 122.000 us; speedup vs baseline: 1.1958x; 1.0384x over previous
//
#include <hip/hip_runtime.h>

// MHA: B=2, S=2048, D=1024, H=16, HD=64, causal, scale=1/8.
// Round 13: (a) gemm256 retiled 256x192 -> grid 16x16 = 256 blocks = exactly
// 1/CU (was 192 blocks: 25% of CUs idle). LDS 112KB, acc[8][3]. (b) cvt_wt
// vectorized (float4 loads, 64x64 tile, ushort4 stores). attn4 / gemm128o /
// cvt_x / trV unchanged from round 12.
//   ws layout (bytes):
//     [0,8M)    Xbf  : x as bf16 [4096,1024]
//     [8M,16M)  WT   : WqT,WkT,WvT,WoT bf16 [1024,1024] each ([N][K])
//     [16M,32M) Q,K  : [B,H,S,HD] bf16
//     [32M,40M) Vt   : [B,H,HD,S] bf16 (written by trV)
//     [40M,48M) CTX  : first V row-major (gemm256 out), then ctx [B,S,D]

#define S_LEN 2048
#define DMODEL 1024
#define NHEAD 16
#define HDIM 64
#define MROWS 4096  // B*S

typedef __bf16 bf16x8 __attribute__((ext_vector_type(8)));
typedef float f32x4 __attribute__((ext_vector_type(4)));
typedef float f32x16 __attribute__((ext_vector_type(16)));

__device__ __forceinline__ ushort f2bf(float f) {
  union { float f; unsigned u; } v; v.f = f;
  unsigned r = v.u + 0x7fffu + ((v.u >> 16) & 1u);  // RNE
  return (ushort)(r >> 16);
}

__device__ __forceinline__ void gload_lds16(const ushort* g, ushort* l) {
  __builtin_amdgcn_global_load_lds(
      (const __attribute__((address_space(1))) void*)g,
      (__attribute__((address_space(3))) void*)l, 16, 0, 0);
}

// pack two f32 -> one dword of 2 bf16 (compiler emits v_cvt_pk_bf16_f32)
__device__ __forceinline__ unsigned pack2bf(float lo, float hi) {
  union { __bf16 h[2]; unsigned u; } t;
  t.h[0] = (__bf16)lo; t.h[1] = (__bf16)hi;
  return t.u;
}

#if __has_builtin(__builtin_amdgcn_permlane32_swap)
#define HAVE_PL32 1
// after call: a = {a.lo | b.lo}, b = {a.hi | b.hi}  (lane<32 | lane>=32)
__device__ __forceinline__ void pl32sw(unsigned& a, unsigned& b) {
  auto r = __builtin_amdgcn_permlane32_swap((int)a, (int)b, false, false);
  a = (unsigned)r[0];
  b = (unsigned)r[1];
}
#endif

__device__ __forceinline__ float halfcomb_max(float x) {
#ifdef HAVE_PL32
  unsigned a = __float_as_uint(x), b = a;
  pl32sw(a, b);
  return fmaxf(__uint_as_float(a), __uint_as_float(b));
#else
  return fmaxf(x, __shfl_xor(x, 32, 64));
#endif
}
__device__ __forceinline__ float halfcomb_sum(float x) {
#ifdef HAVE_PL32
  unsigned a = __float_as_uint(x), b = a;
  pl32sw(a, b);
  return __uint_as_float(a) + __uint_as_float(b);
#else
  return x + __shfl_xor(x, 32, 64);
#endif
}

// ---------------- conversion kernels ----------------

__global__ __launch_bounds__(256) void cvt_x(const float* __restrict__ x,
                                             ushort* __restrict__ xb) {
  int i = (blockIdx.x * 256 + threadIdx.x) * 4;
  float4 v = *(const float4*)&x[i];
  ushort4 o;
  o.x = f2bf(v.x); o.y = f2bf(v.y); o.z = f2bf(v.z); o.w = f2bf(v.w);
  *(ushort4*)&xb[i] = o;
}

// W [K][N] fp32 -> WT [N][K] bf16, 64x64 tiles, vectorized
__global__ __launch_bounds__(256) void cvt_wt(const float* __restrict__ W0,
                                              const float* __restrict__ W1,
                                              const float* __restrict__ W2,
                                              const float* __restrict__ W3,
                                              ushort* __restrict__ out) {
  const float* W = blockIdx.z == 0 ? W0 : blockIdx.z == 1 ? W1
                   : blockIdx.z == 2 ? W2 : W3;
  ushort* WT = out + (size_t)blockIdx.z * DMODEL * DMODEL;
  __shared__ float tile[64][65];
  const int n0 = blockIdx.x * 64, k0 = blockIdx.y * 64;
#pragma unroll
  for (int i = 0; i < 4; ++i) {
    int chunk = i * 256 + threadIdx.x;  // 0..1023
    int r = chunk >> 4, c4 = chunk & 15;  // r: k-row, c4: n-quad
    float4 v = *(const float4*)&W[(size_t)(k0 + r) * DMODEL + n0 + c4 * 4];
    tile[r][c4 * 4 + 0] = v.x; tile[r][c4 * 4 + 1] = v.y;
    tile[r][c4 * 4 + 2] = v.z; tile[r][c4 * 4 + 3] = v.w;
  }
  __syncthreads();
#pragma unroll
  for (int i = 0; i < 4; ++i) {
    int chunk = i * 256 + threadIdx.x;
    int r = chunk >> 4, c4 = chunk & 15;  // r: n-row, c4: k-quad
    ushort4 o;
    o.x = f2bf(tile[c4 * 4 + 0][r]); o.y = f2bf(tile[c4 * 4 + 1][r]);
    o.z = f2bf(tile[c4 * 4 + 2][r]); o.w = f2bf(tile[c4 * 4 + 3][r]);
    *(ushort4*)&WT[(size_t)(n0 + r) * DMODEL + k0 + c4 * 4] = o;
  }
}

// V [B,H,S,HD] -> Vt [B,H,HD,S], 32x32 LDS tiles
__global__ __launch_bounds__(256) void trV(const ushort* __restrict__ V,
                                           ushort* __restrict__ Vt) {
  const int bh = blockIdx.z;
  const ushort* src = V + (size_t)bh * S_LEN * HDIM;
  ushort* dst = Vt + (size_t)bh * HDIM * S_LEN;
  __shared__ ushort tile[32][33];
  int s0 = blockIdx.x * 32, h0 = blockIdx.y * 32;
  int tx = threadIdx.x & 31, ty = threadIdx.x >> 5;  // 32 x 8
#pragma unroll
  for (int i = 0; i < 32; i += 8)
    tile[ty + i][tx] = src[(size_t)(s0 + ty + i) * HDIM + h0 + tx];
  __syncthreads();
#pragma unroll
  for (int i = 0; i < 32; i += 8)
    dst[(size_t)(h0 + ty + i) * S_LEN + s0 + tx] = tile[tx][ty + i];
}

// ---------------- QKV GEMM: 256x192 tile, 8 waves, phase-paced ------------
// A = Xbf [4096,1024]; Bt = WT [3072 rows][1024] (QKV fused).
// Grid 16x16 = 256 blocks = exactly 1/CU. Wave tile 128x48 (acc[8][3]).
__global__ __launch_bounds__(512) void gemm256(
    const ushort* __restrict__ A, const ushort* __restrict__ Bt,
    const float* __restrict__ b0, const float* __restrict__ b1,
    const float* __restrict__ b2, ushort* __restrict__ outQ,
    ushort* __restrict__ outK, ushort* __restrict__ outV) {
  const int flat = blockIdx.y * 16 + blockIdx.x;       // 0..255
  const int swz = (flat & 7) * 32 + (flat >> 3);       // bijective (256=8*32)
  const int bx = swz & 15, by = swz >> 4;
  const int m0 = bx * 256, n0 = by * 192;

  __shared__ __align__(16) ushort Al[2][256 * 64];  // 64 KB
  __shared__ __align__(16) ushort Bl[2][192 * 64];  // 48 KB

  const int tid = threadIdx.x;
  const int lane = tid & 63, wid = tid >> 6;
  const int wr = wid >> 2, wc = wid & 3;   // wave tile: rows wr*128, cols wc*48
  const int fr = lane & 15, hi16 = lane >> 4;

  f32x4 acc[8][3] = {};

  // ---- prologue: stage K-tile 0 into buf 0 ----
#pragma unroll
  for (int l = 0; l < 4; ++l) {
    int chunk = l * 512 + tid;               // 0..2047 over 256x64 A tile
    int row = chunk >> 3, cpos = chunk & 7;
    int scol = (cpos ^ (row & 7)) * 8;
    gload_lds16(&A[(size_t)(m0 + row) * DMODEL + scol], &Al[0][chunk * 8]);
  }
#pragma unroll
  for (int l = 0; l < 3; ++l) {
    int chunk = l * 512 + tid;               // 0..1535 over 192x64 B tile
    int row = chunk >> 3, cpos = chunk & 7;
    int scol = (cpos ^ (row & 7)) * 8;
    gload_lds16(&Bt[(size_t)(n0 + row) * DMODEL + scol], &Bl[0][chunk * 8]);
  }
  __syncthreads();  // vmcnt drained: buf0 ready

  for (int t = 0; t < 16; ++t) {
    const int bt = t & 1;
    bf16x8 bfr[3];
#pragma unroll
    for (int s = 0; s < 4; ++s) {
      const int kk = s >> 1, mh = s & 1;
      bf16x8 af[4];
#pragma unroll
      for (int q = 0; q < 4; ++q) {
        int rl = wr * 128 + (mh * 4 + q) * 16 + fr;
        af[q] = *(const bf16x8*)&Al[bt][rl * 64 +
                                        ((kk * 4 + hi16) ^ (rl & 7)) * 8];
      }
      if (mh == 0) {
#pragma unroll
        for (int nf = 0; nf < 3; ++nf) {
          int rl = wc * 48 + nf * 16 + fr;
          bfr[nf] = *(const bf16x8*)&Bl[bt][rl * 64 +
                                            ((kk * 4 + hi16) ^ (rl & 7)) * 8];
        }
      }
      // stage K-tile t+1 EARLY: full A at s=0, full B at s=1
      if (t + 1 < 16 && s < 2) {
        const int k64 = (t + 1) * 64;
        if (s == 0) {
#pragma unroll
          for (int l = 0; l < 4; ++l) {
            int chunk = l * 512 + tid;
            int row = chunk >> 3, cpos = chunk & 7;
            int scol = (cpos ^ (row & 7)) * 8;
            gload_lds16(&A[(size_t)(m0 + row) * DMODEL + k64 + scol],
                        &Al[bt ^ 1][chunk * 8]);
          }
        } else {
#pragma unroll
          for (int l = 0; l < 3; ++l) {
            int chunk = l * 512 + tid;
            int row = chunk >> 3, cpos = chunk & 7;
            int scol = (cpos ^ (row & 7)) * 8;
            gload_lds16(&Bt[(size_t)(n0 + row) * DMODEL + k64 + scol],
                        &Bl[bt ^ 1][chunk * 8]);
          }
        }
      }
      __builtin_amdgcn_s_barrier();  // pacing
      __builtin_amdgcn_s_setprio(1);
#pragma unroll
      for (int q = 0; q < 4; ++q)
#pragma unroll
        for (int nf = 0; nf < 3; ++nf)
          acc[mh * 4 + q][nf] = __builtin_amdgcn_mfma_f32_16x16x32_bf16(
              af[q], bfr[nf], acc[mh * 4 + q][nf], 0, 0, 0);
      __builtin_amdgcn_s_setprio(0);
      if (s < 3) __builtin_amdgcn_s_barrier();
    }
    __syncthreads();  // buf bt reads done + tile t+1 stage drained
  }

  // ---- epilogue: bias + row-major writes ----
#pragma unroll
  for (int mf = 0; mf < 8; ++mf) {
#pragma unroll
    for (int nf = 0; nf < 3; ++nf) {
      int col = n0 + wc * 48 + nf * 16 + fr;  // 0..3071
      int z = col >> 10, cw = col & 1023;
      float bval = z == 0 ? b0[cw] : z == 1 ? b1[cw] : b2[cw];
      int h = cw >> 6, hd = cw & (HDIM - 1);
      ushort* dst = (z == 0) ? outQ : (z == 1) ? outK : outV;
#pragma unroll
      for (int rg = 0; rg < 4; ++rg) {
        int row = m0 + wr * 128 + mf * 16 + hi16 * 4 + rg;
        int b = row >> 11, sq = row & (S_LEN - 1);
        float val = acc[mf][nf][rg] + bval;
        dst[(((size_t)(b * NHEAD + h)) * S_LEN + sq) * HDIM + hd] = f2bf(val);
      }
    }
  }
}

// ---------------- out-proj GEMM (128x128 tile, BK=64, 2-phase dbuf) -------
__global__ __launch_bounds__(256) void gemm128o(
    const ushort* __restrict__ A, const ushort* __restrict__ Bt,
    const float* __restrict__ b0, float* __restrict__ outB) {
  const int NT = 256;
  const int flat = blockIdx.y * 32 + blockIdx.x;
  const int swz = (flat & 7) * (NT >> 3) + (flat >> 3);
  const int bx = swz & 31, by = swz >> 5;
  const int m0 = bx * 128, n0 = by * 128;

  __shared__ __align__(16) ushort Alds[2][128 * 64];
  __shared__ __align__(16) ushort Blds[2][128 * 64];

  const int tid = threadIdx.x;
  const int lane = tid & 63, w = tid >> 6;
  const int wr = w >> 1, wc = w & 1;
  const int fr = lane & 15, hi16 = lane >> 4;

  f32x4 acc[4][4] = {};

  auto STAGE = [&](int kt, int bi) {
#pragma unroll
    for (int it = 0; it < 4; ++it) {
      int c = it * 256 + tid;
      int row = c >> 3;
      int sc = ((c & 7) ^ (row & 7)) * 8;
      int ldsbase = (it * 256 + w * 64) * 8;
      gload_lds16(&A[(size_t)(m0 + row) * DMODEL + kt + sc],
                  &Alds[bi][ldsbase]);
      gload_lds16(&Bt[(size_t)(n0 + row) * DMODEL + kt + sc],
                  &Blds[bi][ldsbase]);
    }
  };

  auto COMPUTE = [&](int bi) {
#pragma unroll
    for (int kk = 0; kk < 2; ++kk) {
      bf16x8 af[4], bfr[4];
#pragma unroll
      for (int i = 0; i < 4; ++i) {
        int row = wr * 64 + i * 16 + fr;
        af[i] = *(const bf16x8*)&Alds[bi][row * 64 +
                                          ((kk * 4 + hi16) ^ (row & 7)) * 8];
      }
#pragma unroll
      for (int j = 0; j < 4; ++j) {
        int row = wc * 64 + j * 16 + fr;
        bfr[j] = *(const bf16x8*)&Blds[bi][row * 64 +
                                           ((kk * 4 + hi16) ^ (row & 7)) * 8];
      }
#pragma unroll
      for (int i = 0; i < 4; ++i)
#pragma unroll
        for (int j = 0; j < 4; ++j)
          acc[i][j] = __builtin_amdgcn_mfma_f32_16x16x32_bf16(af[i], bfr[j],
                                                              acc[i][j], 0, 0, 0);
    }
  };

  STAGE(0, 0);
  __syncthreads();
  int buf = 0;
  for (int kt = 64; kt < DMODEL; kt += 64) {
    STAGE(kt, buf ^ 1);
    COMPUTE(buf);
    __syncthreads();
    buf ^= 1;
  }
  COMPUTE(buf);

#pragma unroll
  for (int i = 0; i < 4; ++i) {
#pragma unroll
    for (int j = 0; j < 4; ++j) {
      int col = n0 + wc * 64 + j * 16 + fr;
      float bval = b0[col];
#pragma unroll
      for (int r = 0; r < 4; ++r) {
        int row = m0 + wr * 64 + i * 16 + hi16 * 4 + r;
        outB[(size_t)row * DMODEL + col] = acc[i][j][r] + bval;
      }
    }
  }
}

// ---------------- flash attention (causal), split-KV 4-wave ----------------
__global__ __launch_bounds__(256, 2) void attn4(const ushort* __restrict__ Q,
                                                const ushort* __restrict__ K,
                                                const ushort* __restrict__ Vt,
                                                ushort* __restrict__ ctx) {
  const int n = blockIdx.x;
  const int v = (n & 7) * 64 + (n >> 3);  // bijective XCD-contiguous (512=8*64)
  const int ptile = v & 15, bh = v >> 4;
  const int b = bh >> 4, h = bh & 15;
  const int tid = threadIdx.x;
  const int lane = tid & 63, wid = tid >> 6;
  const int p = wid >> 1;        // KV-parity pair: 0 even steps, 1 odd
  const int wq = wid & 1;        // 32-row q-subtile within the 64-row tile
  const int q32 = lane & 31, hi = lane >> 5;
  const bool lo_half = (hi == 0);
  const int tid2 = tid & 127;    // pair-local thread id (2 waves = 128 thr)

  const ushort* Qb = Q + (size_t)bh * S_LEN * HDIM;
  const ushort* Kb = K + (size_t)bh * S_LEN * HDIM;
  const ushort* Vb = Vt + (size_t)bh * HDIM * S_LEN;

  __shared__ __align__(16) ushort Kl[2][2][64 * 64];  // [pair][buf] 32 KB
  __shared__ __align__(16) ushort Vl[2][2][64 * 64];  // 32 KB
  float* scr = (float*)&Kl[0][0][0];  // merge scratch overlay (post-loop only)

  const float C = 0.125f * 1.44269504f;  // scale * log2(e)

  for (int ph = 0; ph < 2; ++ph) {
    const int j = ph ? 31 - ptile : ptile;  // 64-row q-tile index, 0..31
    const int qbase = j * 64 + wq * 32;
    const int qrow = qbase + q32;

    bf16x8 qf[4];
#pragma unroll
    for (int s = 0; s < 4; ++s)
      qf[s] = *(const bf16x8*)&Qb[(size_t)qrow * HDIM + s * 16 + hi * 8];

    f32x16 oacc[2] = {};
    float mraw = -1e30f, lsum = 0.f;
    const int NS = (j >> 1) + 1;  // iterations (pair0 steps; pair1 <= this)

    // prologue: pair p stages its first step (s0 = p) into buf 0
    if (p <= j) {
      const int kv = p * 64;
#pragma unroll
      for (int it = 0; it < 4; ++it) {
        int chunk = it * 128 + tid2;
        int row = chunk >> 3, sc = ((chunk & 7) ^ (row & 7)) * 8;
        gload_lds16(&Kb[(size_t)(kv + row) * HDIM + sc], &Kl[p][0][chunk * 8]);
        gload_lds16(&Vb[(size_t)row * S_LEN + kv + sc], &Vl[p][0][chunk * 8]);
      }
    }
    __syncthreads();

    int buf = 0;
    for (int it = 0; it < NS; ++it) {
      const int s = 2 * it + p;      // my global KV step
      const int kv0 = s * 64;

      // issue my pair's next-tile stage (s+2) first — overlaps compute
      if (s + 2 <= j) {
        const int kvn = kv0 + 128;
#pragma unroll
        for (int st = 0; st < 4; ++st) {
          int chunk = st * 128 + tid2;
          int row = chunk >> 3, sc = ((chunk & 7) ^ (row & 7)) * 8;
          gload_lds16(&Kb[(size_t)(kvn + row) * HDIM + sc],
                      &Kl[p][buf ^ 1][chunk * 8]);
          gload_lds16(&Vb[(size_t)row * S_LEN + kvn + sc],
                      &Vl[p][buf ^ 1][chunk * 8]);
        }
      }

      if (s <= j) {
        // ---- QK^T: S^T[k][q], 2 tiles of 32 k ----
        f32x16 sa[2] = {};
        __builtin_amdgcn_s_setprio(1);
#pragma unroll
        for (int t = 0; t < 2; ++t) {
          const int row = t * 32 + q32;
          const int rsw = (row & 7);
#pragma unroll
          for (int sl = 0; sl < 4; ++sl) {
            bf16x8 kf = *(const bf16x8*)&Kl[p][buf][row * 64 +
                                                    ((sl * 2 + hi) ^ rsw) * 8];
            sa[t] = __builtin_amdgcn_mfma_f32_32x32x16_bf16(kf, qf[sl], sa[t],
                                                            0, 0, 0);
          }
        }
        __builtin_amdgcn_s_setprio(0);

        // ---- V^T A-frags from LDS ----
        bf16x8 vf[2][4];
#pragma unroll
        for (int t2 = 0; t2 < 2; ++t2) {
          const int row = t2 * 32 + q32;
          const int rsw = (row & 7);
#pragma unroll
          for (int sl = 0; sl < 4; ++sl)
            vf[t2][sl] = *(const bf16x8*)&Vl[p][buf][row * 64 +
                                                     ((sl * 2 + hi) ^ rsw) * 8];
        }

        // ---- causal mask (only step s == j masks; wave-uniform) ----
        if (kv0 + 63 > qbase) {
          const int khi = kv0 + 4 * hi;
#pragma unroll
          for (int t = 0; t < 2; ++t)
#pragma unroll
            for (int r = 0; r < 16; ++r) {
              int kg = khi + t * 32 + (r & 3) + 8 * (r >> 2);
              if (kg > qrow) sa[t][r] = -1e30f;
            }
        }

        // ---- online softmax (raw domain; lane-local rows) ----
        float tmv[8];
#pragma unroll
        for (int r = 0; r < 8; ++r)
          tmv[r] = fmaxf(fmaxf(sa[0][r], sa[0][r + 8]),
                         fmaxf(sa[1][r], sa[1][r + 8]));
        float t0 = fmaxf(fmaxf(tmv[0], tmv[1]), fmaxf(tmv[2], tmv[3]));
        float t1 = fmaxf(fmaxf(tmv[4], tmv[5]), fmaxf(tmv[6], tmv[7]));
        float tm = halfcomb_max(fmaxf(t0, t1));

        if (!__all(tm <= mraw + 64.f)) {  // T13 defer-max
          float mnew = fmaxf(mraw, tm);
          float alpha = __builtin_exp2f((mraw - mnew) * C);
          lsum *= alpha;
#pragma unroll
          for (int r = 0; r < 16; ++r) { oacc[0][r] *= alpha; oacc[1][r] *= alpha; }
          mraw = mnew;
        }
        const float mC = mraw * C;
        float psum = 0.f;
#pragma unroll
        for (int t = 0; t < 2; ++t)
#pragma unroll
          for (int r = 0; r < 16; ++r) {
            float pp = __builtin_exp2f(__builtin_fmaf(sa[t][r], C, -mC));
            sa[t][r] = pp;
            psum += pp;
          }
        lsum += halfcomb_sum(psum);

        // ---- P^T -> bf16 B-frags + PV ----
        __builtin_amdgcn_s_setprio(1);
#pragma unroll
        for (int t = 0; t < 2; ++t) {
#pragma unroll
          for (int half = 0; half < 2; ++half) {
            const int rb = half * 8;
            unsigned a0 = pack2bf(sa[t][rb + 0], sa[t][rb + 1]);
            unsigned a1 = pack2bf(sa[t][rb + 2], sa[t][rb + 3]);
            unsigned b0w = pack2bf(sa[t][rb + 4], sa[t][rb + 5]);
            unsigned b1w = pack2bf(sa[t][rb + 6], sa[t][rb + 7]);
            union { unsigned u[4]; bf16x8 v; } pf;
#ifdef HAVE_PL32
            pl32sw(a0, b0w);
            pl32sw(a1, b1w);
            pf.u[0] = a0; pf.u[1] = a1; pf.u[2] = b0w; pf.u[3] = b1w;
#else
            unsigned xa0 = __shfl_xor(a0, 32, 64);
            unsigned xa1 = __shfl_xor(a1, 32, 64);
            unsigned xb0 = __shfl_xor(b0w, 32, 64);
            unsigned xb1 = __shfl_xor(b1w, 32, 64);
            pf.u[0] = lo_half ? a0 : xb0;
            pf.u[1] = lo_half ? a1 : xb1;
            pf.u[2] = lo_half ? xa0 : b0w;
            pf.u[3] = lo_half ? xa1 : b1w;
#endif
            oacc[0] = __builtin_amdgcn_mfma_f32_32x32x16_bf16(
                vf[0][t * 2 + half], pf.v, oacc[0], 0, 0, 0);
            oacc[1] = __builtin_amdgcn_mfma_f32_32x32x16_bf16(
                vf[1][t * 2 + half], pf.v, oacc[1], 0, 0, 0);
          }
        }
        __builtin_amdgcn_s_setprio(0);
      }

      __syncthreads();  // stage complete + LDS reads done before overwrite
      buf ^= 1;
    }

    // ---- merge pair partials: pair1 publishes, pair0 merges + stores ----
    const int base = (wq * 64 + lane) * 37;  // stride-37: conflict-free
    if (p == 1) {
      scr[base + 0] = mraw;
      scr[base + 1] = lsum;
#pragma unroll
      for (int t = 0; t < 2; ++t)
#pragma unroll
        for (int r = 0; r < 16; ++r) scr[base + 2 + t * 16 + r] = oacc[t][r];
    }
    __syncthreads();
    if (p == 0) {
      const float mB = scr[base + 0], lB = scr[base + 1];
      const float mS = fmaxf(mraw, mB);
      const float aA = __builtin_exp2f((mraw - mS) * C);
      const float aB = __builtin_exp2f((mB - mS) * C);
      const float lT = lsum * aA + lB * aB;
      const float linv = 1.0f / lT;
      ushort* crow = &ctx[((size_t)(b * S_LEN) + qrow) * DMODEL + h * HDIM];
#pragma unroll
      for (int t = 0; t < 2; ++t)
#pragma unroll
        for (int g2 = 0; g2 < 4; ++g2) {
          ushort4 o;  // hd = t*32 + g2*8 + hi*4 + r
          float m0 = oacc[t][g2 * 4 + 0] * aA + scr[base + 2 + t * 16 + g2 * 4 + 0] * aB;
          float m1 = oacc[t][g2 * 4 + 1] * aA + scr[base + 2 + t * 16 + g2 * 4 + 1] * aB;
          float m2 = oacc[t][g2 * 4 + 2] * aA + scr[base + 2 + t * 16 + g2 * 4 + 2] * aB;
          float m3 = oacc[t][g2 * 4 + 3] * aA + scr[base + 2 + t * 16 + g2 * 4 + 3] * aB;
          o.x = f2bf(m0 * linv); o.y = f2bf(m1 * linv);
          o.z = f2bf(m2 * linv); o.w = f2bf(m3 * linv);
          *(ushort4*)&crow[t * 32 + g2 * 8 + hi * 4] = o;
        }
    }
    __syncthreads();  // scratch reads done before next phase restages LDS
  }
}

// ---------------- launch ----------------

extern "C" void kernel_launch(void* const* d_in, const int* in_sizes, int n_in,
                              void* d_out, int out_size, void* d_ws,
                              size_t ws_size, hipStream_t stream) {
  const float* x  = (const float*)d_in[0];
  const float* Wq = (const float*)d_in[1];
  const float* bq = (const float*)d_in[2];
  const float* Wk = (const float*)d_in[3];
  const float* bk = (const float*)d_in[4];
  const float* Wv = (const float*)d_in[5];
  const float* bv = (const float*)d_in[6];
  const float* Wo = (const float*)d_in[7];
  const float* bo = (const float*)d_in[8];

  char* ws = (char*)d_ws;
  ushort* Xbf = (ushort*)ws;                               // 8 MB
  ushort* WT  = (ushort*)(ws + (size_t)8 * 1024 * 1024);   // 8 MB
  ushort* QKV = (ushort*)(ws + (size_t)16 * 1024 * 1024);  // Q,K then Vt
  ushort* CTX = (ushort*)(ws + (size_t)40 * 1024 * 1024);  // V-rowmajor, ctx

  const size_t QKV_ELEMS = (size_t)MROWS * DMODEL;  // 4 M elems = 8 MB
  const size_t W_ELEMS = (size_t)DMODEL * DMODEL;

  ushort* Qp  = QKV;                  // [B,H,S,HD]
  ushort* Kp  = QKV + QKV_ELEMS;      // [B,H,S,HD]
  ushort* Vtp = QKV + 2 * QKV_ELEMS;  // [B,H,HD,S]  (trV output)
  ushort* Vrp = CTX;                  // [B,H,S,HD]  (gemm256 scratch out)

  cvt_x<<<4096, 256, 0, stream>>>(x, Xbf);
  cvt_wt<<<dim3(16, 16, 4), 256, 0, stream>>>(Wq, Wk, Wv, Wo, WT);
  gemm256<<<dim3(16, 16), 512, 0, stream>>>(Xbf, WT, bq, bk, bv, Qp, Kp, Vrp);
  trV<<<dim3(64, 2, 32), 256, 0, stream>>>(Vrp, Vtp);
  attn4<<<dim3(512), 256, 0, stream>>>(Qp, Kp, Vtp, CTX);
  gemm128o<<<dim3(32, 8), 256, 0, stream>>>(CTX, WT + 3 * W_ELEMS, bo,
                                            (float*)d_out);
}